// Round 2
// baseline (11981.455 us; speedup 1.0000x reference)
//
#include <hip/hip_runtime.h>

#define N_NODES  100000
#define N_EDGES  3200000
#define N_GRAPHS 3200

// ---------------- bf16 helpers ----------------
__device__ __forceinline__ float bf2f(unsigned short u) {
    return __uint_as_float(((unsigned)u) << 16);
}
__device__ __forceinline__ unsigned short f2bf(float f) {
    unsigned u = __float_as_uint(f);
    u += 0x7fffu + ((u >> 16) & 1u);   // RNE
    return (unsigned short)(u >> 16);
}

// ---------------- CSR build ----------------
__global__ void zero_int_kernel(int* __restrict__ p, int n) {
    int i = blockIdx.x * blockDim.x + threadIdx.x;
    if (i < n) p[i] = 0;
}

__global__ void deg_count_kernel(const int* __restrict__ dst, int* __restrict__ deg, int E) {
    int e = blockIdx.x * blockDim.x + threadIdx.x;
    if (e < E) atomicAdd(&deg[dst[e]], 1);
}

__global__ void scan_offsets_kernel(const int* __restrict__ deg, int* __restrict__ offsets,
                                    int* __restrict__ cursor, int n) {
    __shared__ int part[256];
    int t = threadIdx.x;
    int chunk = (n + 255) / 256;
    int lo = t * chunk; if (lo > n) lo = n;
    int hi = lo + chunk; if (hi > n) hi = n;
    int s = 0;
    for (int i = lo; i < hi; ++i) s += deg[i];
    part[t] = s;
    __syncthreads();
    for (int off = 1; off < 256; off <<= 1) {
        int v = part[t];
        int add = (t >= off) ? part[t - off] : 0;
        __syncthreads();
        part[t] = v + add;
        __syncthreads();
    }
    int run = (t == 0) ? 0 : part[t - 1];
    for (int i = lo; i < hi; ++i) {
        offsets[i] = run;
        cursor[i]  = run;
        run += deg[i];
    }
    if (t == 255) offsets[n] = run;
}

__global__ void fill_csr_kernel(const int* __restrict__ src, const int* __restrict__ dst,
                                int* __restrict__ cursor, int* __restrict__ csr_src, int E) {
    int e = blockIdx.x * blockDim.x + threadIdx.x;
    if (e < E) {
        int d = dst[e];
        int pos = atomicAdd(&cursor[d], 1);
        csr_src[pos] = src[e];
    }
}

__global__ void compute_dis_kernel(const int* __restrict__ deg, float* __restrict__ dis, int n) {
    int i = blockIdx.x * blockDim.x + threadIdx.x;
    if (i < n) dis[i] = rsqrtf((float)deg[i] + 1.0f);
}

// ---------------- GEMM1: x[M×37] @ W1[37×128], out bf16 = acc * dis[row] ----------------
__global__ void gemm1_kernel(const float* __restrict__ x, const float* __restrict__ W,
                             const float* __restrict__ dis, unsigned short* __restrict__ out) {
    __shared__ float lds[16 * 37];
    int row0 = blockIdx.x * 16;
    int t = threadIdx.x;   // 0..127 (= col)
    const float* src = x + (size_t)row0 * 37;
    for (int i = t; i < 16 * 37; i += 128) lds[i] = src[i];
    __syncthreads();
    float acc[16];
#pragma unroll
    for (int r = 0; r < 16; ++r) acc[r] = 0.0f;
#pragma unroll
    for (int k = 0; k < 37; ++k) {
        float wv = W[k * 128 + t];
#pragma unroll
        for (int r = 0; r < 16; ++r) acc[r] += lds[r * 37 + k] * wv;
    }
#pragma unroll
    for (int r = 0; r < 16; ++r) {
        int row = row0 + r;
        out[(size_t)row * 128 + t] = f2bf(acc[r] * dis[row]);
    }
}

// ---------------- aggregation over bf16 table ----------------
// acc = tab[n] + sum_{src->n} tab[src]
// FINISH=1: out = bf16( relu(dis[n]*acc + bias[f]) * dis[n] )   (layer-1 finish + next table)
// FINISH=0: out = bf16( dis[n]*acc )                            (pure propagate)
template<int F, bool FINISH>
__global__ void agg_bf16_kernel(const unsigned short* __restrict__ tab,
                                const int* __restrict__ csr_src,
                                const int* __restrict__ offsets,
                                const float* __restrict__ dis,
                                const float* __restrict__ bias,
                                unsigned short* __restrict__ out) {
    constexpr int V = F / 64;   // 2 (F=128) or 4 (F=256)
    int wave = threadIdx.x >> 6;
    int lane = threadIdx.x & 63;
    int n = blockIdx.x * (blockDim.x >> 6) + wave;

    float acc[V];
    if (F == 128) {
        ushort2 u = ((const ushort2*)(tab + (size_t)n * F))[lane];
        acc[0] = bf2f(u.x); acc[1] = bf2f(u.y);
    } else {
        ushort4 u = ((const ushort4*)(tab + (size_t)n * F))[lane];
        acc[0] = bf2f(u.x); acc[1] = bf2f(u.y); acc[2] = bf2f(u.z); acc[3] = bf2f(u.w);
    }

    int lo = offsets[n], hi = offsets[n + 1];
    for (int j0 = lo; j0 < hi; j0 += 64) {
        int cnt = hi - j0; if (cnt > 64) cnt = 64;
        int myidx = (lane < cnt) ? csr_src[j0 + lane] : 0;
        for (int j = 0; j < cnt; ++j) {
            int s = __shfl(myidx, j);
            if (F == 128) {
                ushort2 u = ((const ushort2*)(tab + (size_t)s * F))[lane];
                acc[0] += bf2f(u.x); acc[1] += bf2f(u.y);
            } else {
                ushort4 u = ((const ushort4*)(tab + (size_t)s * F))[lane];
                acc[0] += bf2f(u.x); acc[1] += bf2f(u.y); acc[2] += bf2f(u.z); acc[3] += bf2f(u.w);
            }
        }
    }

    float d = dis[n];
    if (F == 128) {
        ushort2 o;
        if (FINISH) {
            float v0 = fmaxf(d * acc[0] + bias[lane * 2 + 0], 0.0f) * d;
            float v1 = fmaxf(d * acc[1] + bias[lane * 2 + 1], 0.0f) * d;
            o.x = f2bf(v0); o.y = f2bf(v1);
        } else {
            o.x = f2bf(d * acc[0]); o.y = f2bf(d * acc[1]);
        }
        ((ushort2*)(out + (size_t)n * F))[lane] = o;
    } else {
        ushort4 o;
        if (FINISH) {
            float v0 = fmaxf(d * acc[0] + bias[lane * 4 + 0], 0.0f) * d;
            float v1 = fmaxf(d * acc[1] + bias[lane * 4 + 1], 0.0f) * d;
            float v2 = fmaxf(d * acc[2] + bias[lane * 4 + 2], 0.0f) * d;
            float v3 = fmaxf(d * acc[3] + bias[lane * 4 + 3], 0.0f) * d;
            o.x = f2bf(v0); o.y = f2bf(v1); o.z = f2bf(v2); o.w = f2bf(v3);
        } else {
            o.x = f2bf(d * acc[0]); o.y = f2bf(d * acc[1]);
            o.z = f2bf(d * acc[2]); o.w = f2bf(d * acc[3]);
        }
        ((ushort4*)(out + (size_t)n * F))[lane] = o;
    }
}

// ---------------- tiled GEMM: A bf16 [M×K] @ W fp32 [K×256] + bias, relu ----------------
// TO_TABLE=1: out bf16 = bf16(relu(acc+b) * dis[row]);  TO_TABLE=0: out fp32 = relu(acc+b)
template<int K, bool TO_TABLE>
__global__ void gemm_bf16A_tiled(const unsigned short* __restrict__ A,
                                 const float* __restrict__ W,
                                 const float* __restrict__ bias,
                                 const float* __restrict__ dis,
                                 void* __restrict__ outv) {
    constexpr int N = 256, BR = 32, PK = K + 4, QK = K / 4;
    __shared__ unsigned short lds_a[BR * PK];
    __shared__ float lds_w[16 * 256];
    int t = threadIdx.x;            // 0..255
    int rg = t >> 5;                // 8 row groups of 4 rows
    int cp = t & 31;                // 32 col threads, 8 cols each
    int row0 = blockIdx.x * BR;

    const unsigned short* asrc = A + (size_t)row0 * K;
    for (int i = t; i < BR * QK; i += 256) {
        int r = i / QK, kq = i % QK;
        ushort4 v = *(const ushort4*)(asrc + r * K + kq * 4);
        *(ushort4*)&lds_a[r * PK + kq * 4] = v;
    }

    float acc[4][8];
#pragma unroll
    for (int r = 0; r < 4; ++r)
#pragma unroll
        for (int c = 0; c < 8; ++c) acc[r][c] = 0.0f;

    for (int kc = 0; kc < K; kc += 16) {
        __syncthreads();
        const float* wsrc = W + (size_t)kc * N;
#pragma unroll
        for (int i = 0; i < 4; ++i) {
            int idx = t * 4 + i * 1024;
            *(float4*)&lds_w[idx] = *(const float4*)&wsrc[idx];
        }
        __syncthreads();
#pragma unroll
        for (int k2 = 0; k2 < 16; k2 += 2) {
            float a0[4], a1[4];
#pragma unroll
            for (int r = 0; r < 4; ++r) {
                ushort2 u = *(const ushort2*)&lds_a[(rg * 4 + r) * PK + kc + k2];
                a0[r] = bf2f(u.x); a1[r] = bf2f(u.y);
            }
            float w0[8], w1[8];
            *(float4*)&w0[0] = *(const float4*)&lds_w[k2 * 256 + cp * 8];
            *(float4*)&w0[4] = *(const float4*)&lds_w[k2 * 256 + cp * 8 + 4];
            *(float4*)&w1[0] = *(const float4*)&lds_w[(k2 + 1) * 256 + cp * 8];
            *(float4*)&w1[4] = *(const float4*)&lds_w[(k2 + 1) * 256 + cp * 8 + 4];
#pragma unroll
            for (int r = 0; r < 4; ++r)
#pragma unroll
                for (int c = 0; c < 8; ++c)
                    acc[r][c] += a0[r] * w0[c] + a1[r] * w1[c];
        }
    }

#pragma unroll
    for (int r = 0; r < 4; ++r) {
        int row = row0 + rg * 4 + r;
        float vals[8];
#pragma unroll
        for (int c = 0; c < 8; ++c)
            vals[c] = fmaxf(acc[r][c] + bias[cp * 8 + c], 0.0f);
        if (TO_TABLE) {
            float d = dis[row];
            ushort4 o0, o1;
            o0.x = f2bf(vals[0] * d); o0.y = f2bf(vals[1] * d);
            o0.z = f2bf(vals[2] * d); o0.w = f2bf(vals[3] * d);
            o1.x = f2bf(vals[4] * d); o1.y = f2bf(vals[5] * d);
            o1.z = f2bf(vals[6] * d); o1.w = f2bf(vals[7] * d);
            unsigned short* out = (unsigned short*)outv;
            *(ushort4*)&out[(size_t)row * N + cp * 8]     = o0;
            *(ushort4*)&out[(size_t)row * N + cp * 8 + 4] = o1;
        } else {
            float* out = (float*)outv;
            *(float4*)&out[(size_t)row * N + cp * 8]     = *(float4*)&vals[0];
            *(float4*)&out[(size_t)row * N + cp * 8 + 4] = *(float4*)&vals[4];
        }
    }
}

// ---------------- pooling ----------------
__device__ __forceinline__ int lower_bound_dev(const int* __restrict__ a, int n, int key) {
    int lo = 0, hi = n;
    while (lo < hi) {
        int mid = (lo + hi) >> 1;
        if (a[mid] < key) lo = mid + 1; else hi = mid;
    }
    return lo;
}

__global__ void pool_kernel(const float* __restrict__ h, const int* __restrict__ batch,
                            float* __restrict__ pooled, int nNodes) {
    int g = blockIdx.x;
    int t = threadIdx.x; // 0..255
    __shared__ int bounds[2];
    if (t == 0) bounds[0] = lower_bound_dev(batch, nNodes, g);
    if (t == 1) bounds[1] = lower_bound_dev(batch, nNodes, g + 1);
    __syncthreads();
    int lo = bounds[0], hi = bounds[1];
    float acc = 0.0f;
    for (int n = lo; n < hi; ++n) acc += h[(size_t)n * 256 + t];
    float cnt = (float)(hi - lo);
    pooled[(size_t)g * 256 + t] = acc / fmaxf(cnt, 1.0f);
}

// ---------------- head GEMM (fp32 naive, tiny M) ----------------
__global__ void head_gemm_kernel(const float* __restrict__ H, const float* __restrict__ W,
                                 const float* __restrict__ bias, float* __restrict__ out) {
    __shared__ float lds[16 * 256];
    int row0 = blockIdx.x * 16;
    int t = threadIdx.x;   // 0..255 (= col)
    const float* src = H + (size_t)row0 * 256;
    for (int i = t; i < 16 * 256; i += 256) lds[i] = src[i];
    __syncthreads();
    float acc[16];
#pragma unroll
    for (int r = 0; r < 16; ++r) acc[r] = 0.0f;
#pragma unroll 4
    for (int k = 0; k < 256; ++k) {
        float wv = W[k * 256 + t];
#pragma unroll
        for (int r = 0; r < 16; ++r) acc[r] += lds[r * 256 + k] * wv;
    }
#pragma unroll
    for (int r = 0; r < 16; ++r)
        out[(size_t)(row0 + r) * 256 + t] = acc[r] + bias[t];
}

// ---------------- launch ----------------
static inline size_t align_up(size_t x, size_t a) { return (x + a - 1) & ~(a - 1); }

extern "C" void kernel_launch(void* const* d_in, const int* in_sizes, int n_in,
                              void* d_out, int out_size, void* d_ws, size_t ws_size,
                              hipStream_t stream) {
    const float* x  = (const float*)d_in[0];
    const float* W1 = (const float*)d_in[1];
    const float* b1 = (const float*)d_in[2];
    const float* W2 = (const float*)d_in[3];
    const float* b2 = (const float*)d_in[4];
    const float* W3 = (const float*)d_in[5];
    const float* b3 = (const float*)d_in[6];
    const float* Wp = (const float*)d_in[7];
    const float* bp = (const float*)d_in[8];
    const int*   ei = (const int*)d_in[9];   // [2, E]
    const int*   batch = (const int*)d_in[10];
    float* out = (float*)d_out;

    const int* e_src = ei;
    const int* e_dst = ei + N_EDGES;

    char* p = (char*)d_ws;
    size_t off = 0;
    auto take = [&](size_t bytes) {
        void* r = p + off;
        off = align_up(off + bytes, 256);
        return r;
    };
    int*   deg     = (int*)  take(sizeof(int) * N_NODES);
    int*   offsets = (int*)  take(sizeof(int) * (N_NODES + 1));
    int*   cursor  = (int*)  take(sizeof(int) * N_NODES);
    int*   csr_src = (int*)  take(sizeof(int) * N_EDGES);
    float* dis     = (float*)take(sizeof(float) * N_NODES);
    float* pooled  = (float*)take(sizeof(float) * N_GRAPHS * 256);
    unsigned short* bufX = (unsigned short*)take(sizeof(unsigned short) * (size_t)N_NODES * 256);
    unsigned short* bufY = (unsigned short*)take(sizeof(unsigned short) * (size_t)N_NODES * 256);
    float* h3      = (float*)take(sizeof(float) * (size_t)N_NODES * 256);

    unsigned short* t1     = bufX;                               // [100K×128]
    unsigned short* table2 = bufX + (size_t)N_NODES * 128;       // [100K×128]
    unsigned short* pbuf2  = bufX;                               // overwrite t1
    unsigned short* table3 = bufY;                               // [100K×256]
    unsigned short* pbuf3  = bufX;                               // [100K×256] full X

    const int TB = 256;
    int nodeBlocks = (N_NODES + TB - 1) / TB;
    int edgeBlocks = (N_EDGES + TB - 1) / TB;

    // CSR build
    zero_int_kernel<<<nodeBlocks, TB, 0, stream>>>(deg, N_NODES);
    deg_count_kernel<<<edgeBlocks, TB, 0, stream>>>(e_dst, deg, N_EDGES);
    scan_offsets_kernel<<<1, 256, 0, stream>>>(deg, offsets, cursor, N_NODES);
    fill_csr_kernel<<<edgeBlocks, TB, 0, stream>>>(e_src, e_dst, cursor, csr_src, N_EDGES);
    compute_dis_kernel<<<nodeBlocks, TB, 0, stream>>>(deg, dis, N_NODES);

    // Layer 1 (GEMM-first): t1 = bf16((x@W1)*dis)
    gemm1_kernel<<<N_NODES / 16, 128, 0, stream>>>(x, W1, dis, t1);
    // finish layer 1 + build layer-2 table: table2 = bf16(relu(dis*agg(t1)+b1)*dis)
    agg_bf16_kernel<128, true><<<N_NODES / 4, 256, 0, stream>>>(t1, csr_src, offsets, dis, b1, table2);

    // Layer 2 (propagate-first): pbuf2 = bf16(dis*agg(table2)); h2->table3 via GEMM
    agg_bf16_kernel<128, false><<<N_NODES / 4, 256, 0, stream>>>(table2, csr_src, offsets, dis, nullptr, pbuf2);
    gemm_bf16A_tiled<128, true><<<N_NODES / 32, 256, 0, stream>>>(pbuf2, W2, b2, dis, table3);

    // Layer 3 (propagate-first): pbuf3 = bf16(dis*agg(table3)); h3 = relu(pbuf3@W3+b3)
    agg_bf16_kernel<256, false><<<N_NODES / 4, 256, 0, stream>>>(table3, csr_src, offsets, dis, nullptr, pbuf3);
    gemm_bf16A_tiled<256, false><<<N_NODES / 32, 256, 0, stream>>>(pbuf3, W3, b3, nullptr, h3);

    // pool + head
    pool_kernel<<<N_GRAPHS, 256, 0, stream>>>(h3, batch, pooled, N_NODES);
    head_gemm_kernel<<<N_GRAPHS / 16, 256, 0, stream>>>(pooled, Wp, bp, out);
}

// Round 3
// 2204.216 us; speedup vs baseline: 5.4357x; 5.4357x over previous
//
#include <hip/hip_runtime.h>

#define N_NODES  100000
#define N_EDGES  3200000
#define N_GRAPHS 3200

// ---------------- bf16 helpers ----------------
__device__ __forceinline__ float bf2f(unsigned short u) {
    return __uint_as_float(((unsigned)u) << 16);
}
__device__ __forceinline__ unsigned short f2bf(float f) {
    unsigned u = __float_as_uint(f);
    u += 0x7fffu + ((u >> 16) & 1u);   // RNE
    return (unsigned short)(u >> 16);
}

// ---------------- CSR build ----------------
__global__ void zero_int_kernel(int* __restrict__ p, int n) {
    int i = blockIdx.x * blockDim.x + threadIdx.x;
    if (i < n) p[i] = 0;
}

__global__ void deg_count_kernel(const int* __restrict__ dst, int* __restrict__ deg, int E) {
    int e = blockIdx.x * blockDim.x + threadIdx.x;
    if (e < E) atomicAdd(&deg[dst[e]], 1);
}

__global__ void scan_offsets_kernel(const int* __restrict__ deg, int* __restrict__ offsets,
                                    int* __restrict__ cursor, int n) {
    __shared__ int part[256];
    int t = threadIdx.x;
    int chunk = (n + 255) / 256;
    int lo = t * chunk; if (lo > n) lo = n;
    int hi = lo + chunk; if (hi > n) hi = n;
    int s = 0;
    for (int i = lo; i < hi; ++i) s += deg[i];
    part[t] = s;
    __syncthreads();
    for (int off = 1; off < 256; off <<= 1) {
        int v = part[t];
        int add = (t >= off) ? part[t - off] : 0;
        __syncthreads();
        part[t] = v + add;
        __syncthreads();
    }
    int run = (t == 0) ? 0 : part[t - 1];
    for (int i = lo; i < hi; ++i) {
        offsets[i] = run;
        cursor[i]  = run;
        run += deg[i];
    }
    if (t == 255) offsets[n] = run;
}

__global__ void fill_csr_kernel(const int* __restrict__ src, const int* __restrict__ dst,
                                int* __restrict__ cursor, int* __restrict__ csr_src, int E) {
    int e = blockIdx.x * blockDim.x + threadIdx.x;
    if (e < E) {
        int d = dst[e];
        int pos = atomicAdd(&cursor[d], 1);
        csr_src[pos] = src[e];
    }
}

__global__ void compute_dis_kernel(const int* __restrict__ deg, float* __restrict__ dis, int n) {
    int i = blockIdx.x * blockDim.x + threadIdx.x;
    if (i < n) dis[i] = rsqrtf((float)deg[i] + 1.0f);
}

// ---------------- GEMM1: x[M×37] @ W1[37×128], out bf16 = acc * dis[row] ----------------
__global__ __launch_bounds__(128, 2)
void gemm1_kernel(const float* __restrict__ x, const float* __restrict__ W,
                  const float* __restrict__ dis, unsigned short* __restrict__ out) {
    __shared__ float lds[16 * 37];
    int row0 = blockIdx.x * 16;
    int t = threadIdx.x;   // 0..127 (= col)
    const float* src = x + (size_t)row0 * 37;
    for (int i = t; i < 16 * 37; i += 128) lds[i] = src[i];
    __syncthreads();
    float acc[16];
#pragma unroll
    for (int r = 0; r < 16; ++r) acc[r] = 0.0f;
#pragma unroll
    for (int k = 0; k < 37; ++k) {
        float wv = W[k * 128 + t];
#pragma unroll
        for (int r = 0; r < 16; ++r) acc[r] += lds[r * 37 + k] * wv;
    }
#pragma unroll
    for (int r = 0; r < 16; ++r) {
        int row = row0 + r;
        out[(size_t)row * 128 + t] = f2bf(acc[r] * dis[row]);
    }
}

// ---------------- aggregation over bf16 table ----------------
// acc = tab[n] + sum_{src->n} tab[src]
// FINISH=1: out = bf16( relu(dis[n]*acc + bias[f]) * dis[n] )   (layer-1 finish + next table)
// FINISH=0: out = bf16( dis[n]*acc )                            (pure propagate)
template<int F, bool FINISH>
__global__ __launch_bounds__(256, 4)
void agg_bf16_kernel(const unsigned short* __restrict__ tab,
                     const int* __restrict__ csr_src,
                     const int* __restrict__ offsets,
                     const float* __restrict__ dis,
                     const float* __restrict__ bias,
                     unsigned short* __restrict__ out) {
    constexpr int V = F / 64;   // 2 (F=128) or 4 (F=256)
    int wave = threadIdx.x >> 6;
    int lane = threadIdx.x & 63;
    int n = blockIdx.x * (blockDim.x >> 6) + wave;

    float acc[V];
    if (F == 128) {
        ushort2 u = ((const ushort2*)(tab + (size_t)n * F))[lane];
        acc[0] = bf2f(u.x); acc[1] = bf2f(u.y);
    } else {
        ushort4 u = ((const ushort4*)(tab + (size_t)n * F))[lane];
        acc[0] = bf2f(u.x); acc[1] = bf2f(u.y); acc[2] = bf2f(u.z); acc[3] = bf2f(u.w);
    }

    int lo = offsets[n], hi = offsets[n + 1];
    for (int j0 = lo; j0 < hi; j0 += 64) {
        int cnt = hi - j0; if (cnt > 64) cnt = 64;
        int myidx = (lane < cnt) ? csr_src[j0 + lane] : 0;
        for (int j = 0; j < cnt; ++j) {
            int s = __shfl(myidx, j);
            if (F == 128) {
                ushort2 u = ((const ushort2*)(tab + (size_t)s * F))[lane];
                acc[0] += bf2f(u.x); acc[1] += bf2f(u.y);
            } else {
                ushort4 u = ((const ushort4*)(tab + (size_t)s * F))[lane];
                acc[0] += bf2f(u.x); acc[1] += bf2f(u.y); acc[2] += bf2f(u.z); acc[3] += bf2f(u.w);
            }
        }
    }

    float d = dis[n];
    if (F == 128) {
        ushort2 o;
        if (FINISH) {
            float v0 = fmaxf(d * acc[0] + bias[lane * 2 + 0], 0.0f) * d;
            float v1 = fmaxf(d * acc[1] + bias[lane * 2 + 1], 0.0f) * d;
            o.x = f2bf(v0); o.y = f2bf(v1);
        } else {
            o.x = f2bf(d * acc[0]); o.y = f2bf(d * acc[1]);
        }
        ((ushort2*)(out + (size_t)n * F))[lane] = o;
    } else {
        ushort4 o;
        if (FINISH) {
            float v0 = fmaxf(d * acc[0] + bias[lane * 4 + 0], 0.0f) * d;
            float v1 = fmaxf(d * acc[1] + bias[lane * 4 + 1], 0.0f) * d;
            float v2 = fmaxf(d * acc[2] + bias[lane * 4 + 2], 0.0f) * d;
            float v3 = fmaxf(d * acc[3] + bias[lane * 4 + 3], 0.0f) * d;
            o.x = f2bf(v0); o.y = f2bf(v1); o.z = f2bf(v2); o.w = f2bf(v3);
        } else {
            o.x = f2bf(d * acc[0]); o.y = f2bf(d * acc[1]);
            o.z = f2bf(d * acc[2]); o.w = f2bf(d * acc[3]);
        }
        ((ushort4*)(out + (size_t)n * F))[lane] = o;
    }
}

// ---------------- tiled GEMM: A bf16 [M×K] @ W fp32 [K×256] + bias, relu ----------------
// TO_TABLE=1: out bf16 = bf16(relu(acc+b) * dis[row]);  TO_TABLE=0: out fp32 = relu(acc+b)
template<int K, bool TO_TABLE>
__global__ __launch_bounds__(256, 2)   // VGPR cap 256: micro-kernel needs ~90 live VGPRs, NO spill
void gemm_bf16A_tiled(const unsigned short* __restrict__ A,
                      const float* __restrict__ W,
                      const float* __restrict__ bias,
                      const float* __restrict__ dis,
                      void* __restrict__ outv) {
    constexpr int N = 256, BR = 32, PK = K + 4, QK = K / 4;
    __shared__ unsigned short lds_a[BR * PK];
    __shared__ float lds_w[16 * 256];
    int t = threadIdx.x;            // 0..255
    int rg = t >> 5;                // 8 row groups of 4 rows
    int cp = t & 31;                // 32 col threads, 8 cols each
    int row0 = blockIdx.x * BR;

    const unsigned short* asrc = A + (size_t)row0 * K;
    for (int i = t; i < BR * QK; i += 256) {
        int r = i / QK, kq = i % QK;
        ushort4 v = *(const ushort4*)(asrc + r * K + kq * 4);
        *(ushort4*)&lds_a[r * PK + kq * 4] = v;
    }

    float acc[4][8];
#pragma unroll
    for (int r = 0; r < 4; ++r)
#pragma unroll
        for (int c = 0; c < 8; ++c) acc[r][c] = 0.0f;

    for (int kc = 0; kc < K; kc += 16) {
        __syncthreads();
        const float* wsrc = W + (size_t)kc * N;
#pragma unroll
        for (int i = 0; i < 4; ++i) {
            int idx = t * 4 + i * 1024;
            *(float4*)&lds_w[idx] = *(const float4*)&wsrc[idx];
        }
        __syncthreads();
#pragma unroll
        for (int k2 = 0; k2 < 16; k2 += 2) {
            float a0[4], a1[4];
#pragma unroll
            for (int r = 0; r < 4; ++r) {
                ushort2 u = *(const ushort2*)&lds_a[(rg * 4 + r) * PK + kc + k2];
                a0[r] = bf2f(u.x); a1[r] = bf2f(u.y);
            }
            float w0[8], w1[8];
            *(float4*)&w0[0] = *(const float4*)&lds_w[k2 * 256 + cp * 8];
            *(float4*)&w0[4] = *(const float4*)&lds_w[k2 * 256 + cp * 8 + 4];
            *(float4*)&w1[0] = *(const float4*)&lds_w[(k2 + 1) * 256 + cp * 8];
            *(float4*)&w1[4] = *(const float4*)&lds_w[(k2 + 1) * 256 + cp * 8 + 4];
#pragma unroll
            for (int r = 0; r < 4; ++r)
#pragma unroll
                for (int c = 0; c < 8; ++c)
                    acc[r][c] += a0[r] * w0[c] + a1[r] * w1[c];
        }
    }

#pragma unroll
    for (int r = 0; r < 4; ++r) {
        int row = row0 + rg * 4 + r;
        float vals[8];
#pragma unroll
        for (int c = 0; c < 8; ++c)
            vals[c] = fmaxf(acc[r][c] + bias[cp * 8 + c], 0.0f);
        if (TO_TABLE) {
            float d = dis[row];
            ushort4 o0, o1;
            o0.x = f2bf(vals[0] * d); o0.y = f2bf(vals[1] * d);
            o0.z = f2bf(vals[2] * d); o0.w = f2bf(vals[3] * d);
            o1.x = f2bf(vals[4] * d); o1.y = f2bf(vals[5] * d);
            o1.z = f2bf(vals[6] * d); o1.w = f2bf(vals[7] * d);
            unsigned short* out = (unsigned short*)outv;
            *(ushort4*)&out[(size_t)row * N + cp * 8]     = o0;
            *(ushort4*)&out[(size_t)row * N + cp * 8 + 4] = o1;
        } else {
            float* out = (float*)outv;
            *(float4*)&out[(size_t)row * N + cp * 8]     = *(float4*)&vals[0];
            *(float4*)&out[(size_t)row * N + cp * 8 + 4] = *(float4*)&vals[4];
        }
    }
}

// ---------------- pooling ----------------
__device__ __forceinline__ int lower_bound_dev(const int* __restrict__ a, int n, int key) {
    int lo = 0, hi = n;
    while (lo < hi) {
        int mid = (lo + hi) >> 1;
        if (a[mid] < key) lo = mid + 1; else hi = mid;
    }
    return lo;
}

__global__ __launch_bounds__(256, 4)
void pool_kernel(const float* __restrict__ h, const int* __restrict__ batch,
                 float* __restrict__ pooled, int nNodes) {
    int g = blockIdx.x;
    int t = threadIdx.x; // 0..255
    __shared__ int bounds[2];
    if (t == 0) bounds[0] = lower_bound_dev(batch, nNodes, g);
    if (t == 1) bounds[1] = lower_bound_dev(batch, nNodes, g + 1);
    __syncthreads();
    int lo = bounds[0], hi = bounds[1];
    float acc = 0.0f;
    for (int n = lo; n < hi; ++n) acc += h[(size_t)n * 256 + t];
    float cnt = (float)(hi - lo);
    pooled[(size_t)g * 256 + t] = acc / fmaxf(cnt, 1.0f);
}

// ---------------- head GEMM (fp32 naive, tiny M) ----------------
__global__ __launch_bounds__(256, 2)
void head_gemm_kernel(const float* __restrict__ H, const float* __restrict__ W,
                      const float* __restrict__ bias, float* __restrict__ out) {
    __shared__ float lds[16 * 256];
    int row0 = blockIdx.x * 16;
    int t = threadIdx.x;   // 0..255 (= col)
    const float* src = H + (size_t)row0 * 256;
    for (int i = t; i < 16 * 256; i += 256) lds[i] = src[i];
    __syncthreads();
    float acc[16];
#pragma unroll
    for (int r = 0; r < 16; ++r) acc[r] = 0.0f;
#pragma unroll 4
    for (int k = 0; k < 256; ++k) {
        float wv = W[k * 256 + t];
#pragma unroll
        for (int r = 0; r < 16; ++r) acc[r] += lds[r * 256 + k] * wv;
    }
#pragma unroll
    for (int r = 0; r < 16; ++r)
        out[(size_t)(row0 + r) * 256 + t] = acc[r] + bias[t];
}

// ---------------- launch ----------------
static inline size_t align_up(size_t x, size_t a) { return (x + a - 1) & ~(a - 1); }

extern "C" void kernel_launch(void* const* d_in, const int* in_sizes, int n_in,
                              void* d_out, int out_size, void* d_ws, size_t ws_size,
                              hipStream_t stream) {
    const float* x  = (const float*)d_in[0];
    const float* W1 = (const float*)d_in[1];
    const float* b1 = (const float*)d_in[2];
    const float* W2 = (const float*)d_in[3];
    const float* b2 = (const float*)d_in[4];
    const float* W3 = (const float*)d_in[5];
    const float* b3 = (const float*)d_in[6];
    const float* Wp = (const float*)d_in[7];
    const float* bp = (const float*)d_in[8];
    const int*   ei = (const int*)d_in[9];   // [2, E]
    const int*   batch = (const int*)d_in[10];
    float* out = (float*)d_out;

    const int* e_src = ei;
    const int* e_dst = ei + N_EDGES;

    char* p = (char*)d_ws;
    size_t off = 0;
    auto take = [&](size_t bytes) {
        void* r = p + off;
        off = align_up(off + bytes, 256);
        return r;
    };
    int*   deg     = (int*)  take(sizeof(int) * N_NODES);
    int*   offsets = (int*)  take(sizeof(int) * (N_NODES + 1));
    int*   cursor  = (int*)  take(sizeof(int) * N_NODES);
    int*   csr_src = (int*)  take(sizeof(int) * N_EDGES);
    float* dis     = (float*)take(sizeof(float) * N_NODES);
    float* pooled  = (float*)take(sizeof(float) * N_GRAPHS * 256);
    unsigned short* bufX = (unsigned short*)take(sizeof(unsigned short) * (size_t)N_NODES * 256);
    unsigned short* bufY = (unsigned short*)take(sizeof(unsigned short) * (size_t)N_NODES * 256);
    float* h3      = (float*)take(sizeof(float) * (size_t)N_NODES * 256);

    unsigned short* t1     = bufX;                               // [100K×128]
    unsigned short* table2 = bufX + (size_t)N_NODES * 128;       // [100K×128]
    unsigned short* pbuf2  = bufX;                               // overwrite t1
    unsigned short* table3 = bufY;                               // [100K×256]
    unsigned short* pbuf3  = bufX;                               // [100K×256] full X

    const int TB = 256;
    int nodeBlocks = (N_NODES + TB - 1) / TB;
    int edgeBlocks = (N_EDGES + TB - 1) / TB;

    // CSR build
    zero_int_kernel<<<nodeBlocks, TB, 0, stream>>>(deg, N_NODES);
    deg_count_kernel<<<edgeBlocks, TB, 0, stream>>>(e_dst, deg, N_EDGES);
    scan_offsets_kernel<<<1, 256, 0, stream>>>(deg, offsets, cursor, N_NODES);
    fill_csr_kernel<<<edgeBlocks, TB, 0, stream>>>(e_src, e_dst, cursor, csr_src, N_EDGES);
    compute_dis_kernel<<<nodeBlocks, TB, 0, stream>>>(deg, dis, N_NODES);

    // Layer 1 (GEMM-first): t1 = bf16((x@W1)*dis)
    gemm1_kernel<<<N_NODES / 16, 128, 0, stream>>>(x, W1, dis, t1);
    // finish layer 1 + build layer-2 table: table2 = bf16(relu(dis*agg(t1)+b1)*dis)
    agg_bf16_kernel<128, true><<<N_NODES / 4, 256, 0, stream>>>(t1, csr_src, offsets, dis, b1, table2);

    // Layer 2 (propagate-first): pbuf2 = bf16(dis*agg(table2)); h2->table3 via GEMM
    agg_bf16_kernel<128, false><<<N_NODES / 4, 256, 0, stream>>>(table2, csr_src, offsets, dis, nullptr, pbuf2);
    gemm_bf16A_tiled<128, true><<<N_NODES / 32, 256, 0, stream>>>(pbuf2, W2, b2, dis, table3);

    // Layer 3 (propagate-first): pbuf3 = bf16(dis*agg(table3)); h3 = relu(pbuf3@W3+b3)
    agg_bf16_kernel<256, false><<<N_NODES / 4, 256, 0, stream>>>(table3, csr_src, offsets, dis, nullptr, pbuf3);
    gemm_bf16A_tiled<256, false><<<N_NODES / 32, 256, 0, stream>>>(pbuf3, W3, b3, nullptr, h3);

    // pool + head
    pool_kernel<<<N_GRAPHS, 256, 0, stream>>>(h3, batch, pooled, N_NODES);
    head_gemm_kernel<<<N_GRAPHS / 16, 256, 0, stream>>>(pooled, Wp, bp, out);
}

// Round 4
// 1409.307 us; speedup vs baseline: 8.5017x; 1.5640x over previous
//
#include <hip/hip_runtime.h>

#define N_NODES  100000
#define N_EDGES  3200000
#define N_GRAPHS 3200

typedef __attribute__((ext_vector_type(8))) short bf16x8;
typedef __attribute__((ext_vector_type(4))) float f32x4;

// ---------------- bf16 helpers ----------------
__device__ __forceinline__ float bf2f(unsigned short u) {
    return __uint_as_float(((unsigned)u) << 16);
}
__device__ __forceinline__ unsigned short f2bf(float f) {
    unsigned u = __float_as_uint(f);
    u += 0x7fffu + ((u >> 16) & 1u);   // RNE
    return (unsigned short)(u >> 16);
}

// ---------------- CSR build ----------------
__global__ void zero_int_kernel(int* __restrict__ p, int n) {
    int i = blockIdx.x * blockDim.x + threadIdx.x;
    if (i < n) p[i] = 0;
}

__global__ void deg_count_kernel(const int* __restrict__ dst, int* __restrict__ deg, int E) {
    int e = blockIdx.x * blockDim.x + threadIdx.x;
    if (e < E) atomicAdd(&deg[dst[e]], 1);
}

__global__ void scan_offsets_kernel(const int* __restrict__ deg, int* __restrict__ offsets,
                                    int* __restrict__ cursor, int n) {
    __shared__ int part[256];
    int t = threadIdx.x;
    int chunk = (n + 255) / 256;
    int lo = t * chunk; if (lo > n) lo = n;
    int hi = lo + chunk; if (hi > n) hi = n;
    int s = 0;
    for (int i = lo; i < hi; ++i) s += deg[i];
    part[t] = s;
    __syncthreads();
    for (int off = 1; off < 256; off <<= 1) {
        int v = part[t];
        int add = (t >= off) ? part[t - off] : 0;
        __syncthreads();
        part[t] = v + add;
        __syncthreads();
    }
    int run = (t == 0) ? 0 : part[t - 1];
    for (int i = lo; i < hi; ++i) {
        offsets[i] = run;
        cursor[i]  = run;
        run += deg[i];
    }
    if (t == 255) offsets[n] = run;
}

__global__ void fill_csr_kernel(const int* __restrict__ src, const int* __restrict__ dst,
                                int* __restrict__ cursor, int* __restrict__ csr_src, int E) {
    int e = blockIdx.x * blockDim.x + threadIdx.x;
    if (e < E) {
        int d = dst[e];
        int pos = atomicAdd(&cursor[d], 1);
        csr_src[pos] = src[e];
    }
}

__global__ void compute_dis_kernel(const int* __restrict__ deg, float* __restrict__ dis, int n) {
    int i = blockIdx.x * blockDim.x + threadIdx.x;
    if (i < n) dis[i] = rsqrtf((float)deg[i] + 1.0f);
}

// ---------------- pack W[K x 256] fp32 -> split bf16 planes in MFMA B-frag layout ----------
// Bp layout: element j of lane l of k-step s of n-tile t at ((t*KS + s)*64 + l)*8 + j
// maps to W[k = s*32 + (l>>4)*8 + j][n = t*16 + (l&15)]
template<int K>
__global__ void pack_w_kernel(const float* __restrict__ W,
                              unsigned short* __restrict__ hi,
                              unsigned short* __restrict__ lo) {
    constexpr int KS = K / 32;
    int idx = blockIdx.x * blockDim.x + threadIdx.x;
    if (idx >= 16 * KS * 64) return;
    int l = idx & 63;
    int s = (idx >> 6) % KS;
    int t = idx / (64 * KS);
    int k0 = s * 32 + (l >> 4) * 8;
    int n  = t * 16 + (l & 15);
    size_t base = (size_t)idx * 8;
#pragma unroll
    for (int j = 0; j < 8; ++j) {
        float w = W[(size_t)(k0 + j) * 256 + n];
        unsigned short h = f2bf(w);
        float rem = w - bf2f(h);
        hi[base + j] = h;
        lo[base + j] = f2bf(rem);
    }
}

// ---------------- GEMM1: x[M×37] @ W1[37×128], out bf16 = acc * dis[row] ----------------
__global__ __launch_bounds__(128, 2)
void gemm1_kernel(const float* __restrict__ x, const float* __restrict__ W,
                  const float* __restrict__ dis, unsigned short* __restrict__ out) {
    __shared__ float lds[16 * 37];
    int row0 = blockIdx.x * 16;
    int t = threadIdx.x;   // 0..127 (= col)
    const float* src = x + (size_t)row0 * 37;
    for (int i = t; i < 16 * 37; i += 128) lds[i] = src[i];
    __syncthreads();
    float acc[16];
#pragma unroll
    for (int r = 0; r < 16; ++r) acc[r] = 0.0f;
#pragma unroll
    for (int k = 0; k < 37; ++k) {
        float wv = W[k * 128 + t];
#pragma unroll
        for (int r = 0; r < 16; ++r) acc[r] += lds[r * 37 + k] * wv;
    }
#pragma unroll
    for (int r = 0; r < 16; ++r) {
        int row = row0 + r;
        out[(size_t)row * 128 + t] = f2bf(acc[r] * dis[row]);
    }
}

// ---------------- aggregation over bf16 table ----------------
template<int F, bool FINISH>
__global__ __launch_bounds__(256, 4)
void agg_bf16_kernel(const unsigned short* __restrict__ tab,
                     const int* __restrict__ csr_src,
                     const int* __restrict__ offsets,
                     const float* __restrict__ dis,
                     const float* __restrict__ bias,
                     unsigned short* __restrict__ out) {
    int wave = threadIdx.x >> 6;
    int lane = threadIdx.x & 63;
    int n = blockIdx.x * (blockDim.x >> 6) + wave;

    float acc[F / 64];
    if (F == 128) {
        ushort2 u = ((const ushort2*)(tab + (size_t)n * F))[lane];
        acc[0] = bf2f(u.x); acc[1] = bf2f(u.y);
    } else {
        ushort4 u = ((const ushort4*)(tab + (size_t)n * F))[lane];
        acc[0] = bf2f(u.x); acc[1] = bf2f(u.y); acc[2] = bf2f(u.z); acc[3] = bf2f(u.w);
    }

    int lo = offsets[n], hi = offsets[n + 1];
    for (int j0 = lo; j0 < hi; j0 += 64) {
        int cnt = hi - j0; if (cnt > 64) cnt = 64;
        int myidx = (lane < cnt) ? csr_src[j0 + lane] : 0;
        for (int j = 0; j < cnt; ++j) {
            int s = __shfl(myidx, j);
            if (F == 128) {
                ushort2 u = ((const ushort2*)(tab + (size_t)s * F))[lane];
                acc[0] += bf2f(u.x); acc[1] += bf2f(u.y);
            } else {
                ushort4 u = ((const ushort4*)(tab + (size_t)s * F))[lane];
                acc[0] += bf2f(u.x); acc[1] += bf2f(u.y); acc[2] += bf2f(u.z); acc[3] += bf2f(u.w);
            }
        }
    }

    float d = dis[n];
    if (F == 128) {
        ushort2 o;
        if (FINISH) {
            o.x = f2bf(fmaxf(d * acc[0] + bias[lane * 2 + 0], 0.0f) * d);
            o.y = f2bf(fmaxf(d * acc[1] + bias[lane * 2 + 1], 0.0f) * d);
        } else {
            o.x = f2bf(d * acc[0]); o.y = f2bf(d * acc[1]);
        }
        ((ushort2*)(out + (size_t)n * F))[lane] = o;
    } else {
        ushort4 o;
        if (FINISH) {
            o.x = f2bf(fmaxf(d * acc[0] + bias[lane * 4 + 0], 0.0f) * d);
            o.y = f2bf(fmaxf(d * acc[1] + bias[lane * 4 + 1], 0.0f) * d);
            o.z = f2bf(fmaxf(d * acc[2] + bias[lane * 4 + 2], 0.0f) * d);
            o.w = f2bf(fmaxf(d * acc[3] + bias[lane * 4 + 3], 0.0f) * d);
        } else {
            o.x = f2bf(d * acc[0]); o.y = f2bf(d * acc[1]);
            o.z = f2bf(d * acc[2]); o.w = f2bf(d * acc[3]);
        }
        ((ushort4*)(out + (size_t)n * F))[lane] = o;
    }
}

// ---------------- MFMA GEMM: A bf16 [M×K] @ (Whi+Wlo) [K×256] + bias, relu ---------------
// Block: 32 rows × 256 cols, 4 waves (wave w owns cols w*64..w*64+63 as 4 n-tiles).
// No LDS. A-frag: row-major direct load (lane: row=l&15, k=(l>>4)*8+j).
// B-frag: packed planes (see pack_w_kernel). Epilogue: C/D col=l&15, row=(l>>4)*4+r.
// TO_TABLE=1: out bf16 = bf16(relu(acc+b) * dis[row]);  TO_TABLE=0: out fp32 = relu(acc+b)
template<int K, bool TO_TABLE>
__global__ __launch_bounds__(256, 4)
void mfma_gemm_kernel(const unsigned short* __restrict__ A,
                      const unsigned short* __restrict__ Bhi,
                      const unsigned short* __restrict__ Blo,
                      const float* __restrict__ bias,
                      const float* __restrict__ dis,
                      void* __restrict__ outv) {
    constexpr int KS = K / 32;
    int l   = threadIdx.x & 63;
    int wid = threadIdx.x >> 6;      // 0..3
    int n0  = wid * 64;
    int m0  = blockIdx.x * 32;

    f32x4 acc0[4], acc1[4];
#pragma unroll
    for (int tn = 0; tn < 4; ++tn) { acc0[tn] = (f32x4){0,0,0,0}; acc1[tn] = (f32x4){0,0,0,0}; }

    const unsigned short* a0 = A + (size_t)(m0 + (l & 15)) * K + (l >> 4) * 8;
    const unsigned short* a1 = a0 + (size_t)16 * K;

#pragma unroll
    for (int s = 0; s < KS; ++s) {
        bf16x8 af0 = *(const bf16x8*)(a0 + s * 32);
        bf16x8 af1 = *(const bf16x8*)(a1 + s * 32);
#pragma unroll
        for (int tn = 0; tn < 4; ++tn) {
            int t = (n0 >> 4) + tn;
            size_t boff = ((size_t)(t * KS + s) * 64 + l) * 8;
            bf16x8 bh = *(const bf16x8*)(Bhi + boff);
            bf16x8 bl = *(const bf16x8*)(Blo + boff);
            acc0[tn] = __builtin_amdgcn_mfma_f32_16x16x32_bf16(af0, bh, acc0[tn], 0, 0, 0);
            acc0[tn] = __builtin_amdgcn_mfma_f32_16x16x32_bf16(af0, bl, acc0[tn], 0, 0, 0);
            acc1[tn] = __builtin_amdgcn_mfma_f32_16x16x32_bf16(af1, bh, acc1[tn], 0, 0, 0);
            acc1[tn] = __builtin_amdgcn_mfma_f32_16x16x32_bf16(af1, bl, acc1[tn], 0, 0, 0);
        }
    }

    int rowg = (l >> 4) * 4;
#pragma unroll
    for (int tn = 0; tn < 4; ++tn) {
        int n = n0 + tn * 16 + (l & 15);
        float b = bias[n];
#pragma unroll
        for (int r = 0; r < 4; ++r) {
            {
                int m = m0 + rowg + r;
                float v = fmaxf(acc0[tn][r] + b, 0.0f);
                if (TO_TABLE) ((unsigned short*)outv)[(size_t)m * 256 + n] = f2bf(v * dis[m]);
                else          ((float*)outv)[(size_t)m * 256 + n] = v;
            }
            {
                int m = m0 + 16 + rowg + r;
                float v = fmaxf(acc1[tn][r] + b, 0.0f);
                if (TO_TABLE) ((unsigned short*)outv)[(size_t)m * 256 + n] = f2bf(v * dis[m]);
                else          ((float*)outv)[(size_t)m * 256 + n] = v;
            }
        }
    }
}

// ---------------- pooling ----------------
__device__ __forceinline__ int lower_bound_dev(const int* __restrict__ a, int n, int key) {
    int lo = 0, hi = n;
    while (lo < hi) {
        int mid = (lo + hi) >> 1;
        if (a[mid] < key) lo = mid + 1; else hi = mid;
    }
    return lo;
}

__global__ __launch_bounds__(256, 4)
void pool_kernel(const float* __restrict__ h, const int* __restrict__ batch,
                 float* __restrict__ pooled, int nNodes) {
    int g = blockIdx.x;
    int t = threadIdx.x; // 0..255
    __shared__ int bounds[2];
    if (t == 0) bounds[0] = lower_bound_dev(batch, nNodes, g);
    if (t == 1) bounds[1] = lower_bound_dev(batch, nNodes, g + 1);
    __syncthreads();
    int lo = bounds[0], hi = bounds[1];
    float acc = 0.0f;
    for (int n = lo; n < hi; ++n) acc += h[(size_t)n * 256 + t];
    float cnt = (float)(hi - lo);
    pooled[(size_t)g * 256 + t] = acc / fmaxf(cnt, 1.0f);
}

// ---------------- head GEMM (fp32 naive, tiny M) ----------------
__global__ __launch_bounds__(256, 2)
void head_gemm_kernel(const float* __restrict__ H, const float* __restrict__ W,
                      const float* __restrict__ bias, float* __restrict__ out) {
    __shared__ float lds[16 * 256];
    int row0 = blockIdx.x * 16;
    int t = threadIdx.x;   // 0..255 (= col)
    const float* src = H + (size_t)row0 * 256;
    for (int i = t; i < 16 * 256; i += 256) lds[i] = src[i];
    __syncthreads();
    float acc[16];
#pragma unroll
    for (int r = 0; r < 16; ++r) acc[r] = 0.0f;
#pragma unroll 4
    for (int k = 0; k < 256; ++k) {
        float wv = W[k * 256 + t];
#pragma unroll
        for (int r = 0; r < 16; ++r) acc[r] += lds[r * 256 + k] * wv;
    }
#pragma unroll
    for (int r = 0; r < 16; ++r)
        out[(size_t)(row0 + r) * 256 + t] = acc[r] + bias[t];
}

// ---------------- launch ----------------
static inline size_t align_up(size_t x, size_t a) { return (x + a - 1) & ~(a - 1); }

extern "C" void kernel_launch(void* const* d_in, const int* in_sizes, int n_in,
                              void* d_out, int out_size, void* d_ws, size_t ws_size,
                              hipStream_t stream) {
    const float* x  = (const float*)d_in[0];
    const float* W1 = (const float*)d_in[1];
    const float* b1 = (const float*)d_in[2];
    const float* W2 = (const float*)d_in[3];
    const float* b2 = (const float*)d_in[4];
    const float* W3 = (const float*)d_in[5];
    const float* b3 = (const float*)d_in[6];
    const float* Wp = (const float*)d_in[7];
    const float* bp = (const float*)d_in[8];
    const int*   ei = (const int*)d_in[9];   // [2, E]
    const int*   batch = (const int*)d_in[10];
    float* out = (float*)d_out;

    const int* e_src = ei;
    const int* e_dst = ei + N_EDGES;

    char* p = (char*)d_ws;
    size_t off = 0;
    auto take = [&](size_t bytes) {
        void* r = p + off;
        off = align_up(off + bytes, 256);
        return r;
    };
    int*   deg     = (int*)  take(sizeof(int) * N_NODES);
    int*   offsets = (int*)  take(sizeof(int) * (N_NODES + 1));
    int*   cursor  = (int*)  take(sizeof(int) * N_NODES);
    int*   csr_src = (int*)  take(sizeof(int) * N_EDGES);
    float* dis     = (float*)take(sizeof(float) * N_NODES);
    float* pooled  = (float*)take(sizeof(float) * N_GRAPHS * 256);
    unsigned short* whi2 = (unsigned short*)take(sizeof(unsigned short) * 128 * 256);
    unsigned short* wlo2 = (unsigned short*)take(sizeof(unsigned short) * 128 * 256);
    unsigned short* whi3 = (unsigned short*)take(sizeof(unsigned short) * 256 * 256);
    unsigned short* wlo3 = (unsigned short*)take(sizeof(unsigned short) * 256 * 256);
    unsigned short* bufX = (unsigned short*)take(sizeof(unsigned short) * (size_t)N_NODES * 256);
    unsigned short* bufY = (unsigned short*)take(sizeof(unsigned short) * (size_t)N_NODES * 256);
    float* h3      = (float*)take(sizeof(float) * (size_t)N_NODES * 256);

    unsigned short* t1     = bufX;                               // [100K×128]
    unsigned short* table2 = bufX + (size_t)N_NODES * 128;       // [100K×128]
    unsigned short* pbuf2  = bufX;                               // overwrite t1
    unsigned short* table3 = bufY;                               // [100K×256]
    unsigned short* pbuf3  = bufX;                               // [100K×256] full X

    const int TB = 256;
    int nodeBlocks = (N_NODES + TB - 1) / TB;
    int edgeBlocks = (N_EDGES + TB - 1) / TB;

    // CSR build
    zero_int_kernel<<<nodeBlocks, TB, 0, stream>>>(deg, N_NODES);
    deg_count_kernel<<<edgeBlocks, TB, 0, stream>>>(e_dst, deg, N_EDGES);
    scan_offsets_kernel<<<1, 256, 0, stream>>>(deg, offsets, cursor, N_NODES);
    fill_csr_kernel<<<edgeBlocks, TB, 0, stream>>>(e_src, e_dst, cursor, csr_src, N_EDGES);
    compute_dis_kernel<<<nodeBlocks, TB, 0, stream>>>(deg, dis, N_NODES);

    // pack W2/W3 into MFMA B-frag split-bf16 planes
    pack_w_kernel<128><<<(16 * 4 * 64 + 255) / 256, 256, 0, stream>>>(W2, whi2, wlo2);
    pack_w_kernel<256><<<(16 * 8 * 64 + 255) / 256, 256, 0, stream>>>(W3, whi3, wlo3);

    // Layer 1 (GEMM-first): t1 = bf16((x@W1)*dis)
    gemm1_kernel<<<N_NODES / 16, 128, 0, stream>>>(x, W1, dis, t1);
    agg_bf16_kernel<128, true><<<N_NODES / 4, 256, 0, stream>>>(t1, csr_src, offsets, dis, b1, table2);

    // Layer 2 (propagate-first): pbuf2 = bf16(dis*agg(table2)); table3 = bf16(relu(pbuf2@W2+b2)*dis)
    agg_bf16_kernel<128, false><<<N_NODES / 4, 256, 0, stream>>>(table2, csr_src, offsets, dis, nullptr, pbuf2);
    mfma_gemm_kernel<128, true><<<N_NODES / 32, 256, 0, stream>>>(pbuf2, whi2, wlo2, b2, dis, table3);

    // Layer 3 (propagate-first): pbuf3 = bf16(dis*agg(table3)); h3 = relu(pbuf3@W3+b3)
    agg_bf16_kernel<256, false><<<N_NODES / 4, 256, 0, stream>>>(table3, csr_src, offsets, dis, nullptr, pbuf3);
    mfma_gemm_kernel<256, false><<<N_NODES / 32, 256, 0, stream>>>(pbuf3, whi3, wlo3, b3, nullptr, h3);

    // pool + head
    pool_kernel<<<N_GRAPHS, 256, 0, stream>>>(h3, batch, pooled, N_NODES);
    head_gemm_kernel<<<N_GRAPHS / 16, 256, 0, stream>>>(pooled, Wp, bp, out);
}

// Round 5
// 817.195 us; speedup vs baseline: 14.6617x; 1.7246x over previous
//
#include <hip/hip_runtime.h>

#define N_NODES  100000
#define N_EDGES  3200000
#define N_GRAPHS 3200

// CSR-build constants
#define NBLK 200            // edge-chunk blocks
#define EB   16000          // edges per chunk (NBLK*EB == N_EDGES)
#define BSH  7              // bucket = dst >> 7  (128 nodes/bucket)
#define NB   ((N_NODES + 127) >> BSH)   // 782 buckets
#define BCAP 5120           // max edges per bucket staged in LDS (mean 4096, sigma 64)

typedef __attribute__((ext_vector_type(8))) short bf16x8;
typedef __attribute__((ext_vector_type(4))) float f32x4;

// ---------------- bf16 helpers ----------------
__device__ __forceinline__ float bf2f(unsigned short u) {
    return __uint_as_float(((unsigned)u) << 16);
}
__device__ __forceinline__ unsigned short f2bf(float f) {
    unsigned u = __float_as_uint(f);
    u += 0x7fffu + ((u >> 16) & 1u);   // RNE
    return (unsigned short)(u >> 16);
}

// ================= CSR build (counting sort, no global atomics) =================

// Pass 1: per-chunk bucket histogram. hist layout: [NB][NBLK]
__global__ __launch_bounds__(256, 4)
void hist_kernel(const int* __restrict__ dst, int* __restrict__ hist) {
    __shared__ int lh[NB];
    int blk = blockIdx.x, t = threadIdx.x;
    for (int b = t; b < NB; b += 256) lh[b] = 0;
    __syncthreads();
    int e0 = blk * EB;
    for (int i = t; i < EB; i += 256)
        atomicAdd(&lh[dst[e0 + i] >> BSH], 1);
    __syncthreads();
    for (int b = t; b < NB; b += 256) hist[b * NBLK + blk] = lh[b];
}

// Pass 2a: bucket totals (one 64-thread block per bucket)
__global__ void bucket_tot_kernel(const int* __restrict__ hist, int* __restrict__ tot) {
    int b = blockIdx.x, l = threadIdx.x;   // 64 threads
    int s = 0;
    for (int k = l; k < NBLK; k += 64) s += hist[b * NBLK + k];
    for (int off = 32; off; off >>= 1) s += __shfl_down(s, off);
    if (l == 0) tot[b] = s;
}

// Pass 2b: exclusive scan over bucket totals (single block)
__global__ void bucket_scan_kernel(const int* __restrict__ tot, int* __restrict__ bucketStart) {
    __shared__ int part[256];
    int t = threadIdx.x;
    int chunk = (NB + 255) / 256;
    int lo = t * chunk; if (lo > NB) lo = NB;
    int hi = lo + chunk; if (hi > NB) hi = NB;
    int s = 0;
    for (int i = lo; i < hi; ++i) s += tot[i];
    part[t] = s;
    __syncthreads();
    for (int off = 1; off < 256; off <<= 1) {
        int v = part[t];
        int a = (t >= off) ? part[t - off] : 0;
        __syncthreads();
        part[t] = v + a;
        __syncthreads();
    }
    int run = (t == 0) ? 0 : part[t - 1];
    for (int i = lo; i < hi; ++i) { bucketStart[i] = run; run += tot[i]; }
    if (t == 255) bucketStart[NB] = run;
}

// Pass 2c: per-(bucket,chunk) base = bucketStart + running sum over chunks (in-place hist->base)
__global__ void bucket_base_kernel(int* __restrict__ hist, const int* __restrict__ bucketStart) {
    int b = blockIdx.x * blockDim.x + threadIdx.x;
    if (b >= NB) return;
    int run = bucketStart[b];
    int* row = hist + b * NBLK;
#pragma unroll 4
    for (int k = 0; k < NBLK; ++k) { int v = row[k]; row[k] = run; run += v; }
}

// Pass 3: scatter edges into bucket-sorted order (LDS cursors, no global atomics)
__global__ __launch_bounds__(256, 4)
void scatter1_kernel(const int* __restrict__ src, const int* __restrict__ dst,
                     const int* __restrict__ base,
                     int* __restrict__ sdst, int* __restrict__ ssrc) {
    __shared__ int lcur[NB];
    int blk = blockIdx.x, t = threadIdx.x;
    for (int b = t; b < NB; b += 256) lcur[b] = base[b * NBLK + blk];
    __syncthreads();
    int e0 = blk * EB;
    for (int i = t; i < EB; i += 256) {
        int d = dst[e0 + i], s = src[e0 + i];
        int pos = atomicAdd(&lcur[d >> BSH], 1);
        sdst[pos] = d;
        ssrc[pos] = s;
    }
}

// Pass 4: per-bucket node-level CSR entirely in LDS; emits offsets, dis, csr_src
__global__ __launch_bounds__(256, 1)
void csr2_kernel(const int* __restrict__ sdst, const int* __restrict__ ssrc,
                 const int* __restrict__ bucketStart,
                 int* __restrict__ offsets, float* __restrict__ dis,
                 int* __restrict__ csr_src) {
    __shared__ int ldst[BCAP];
    __shared__ int lsrc[BCAP];
    __shared__ int lhist[128], loff[128], lcur[128];
    int b = blockIdx.x, t = threadIdx.x;
    int n0 = b << BSH;
    int e0 = bucketStart[b], e1 = bucketStart[b + 1];
    int cnt = e1 - e0; if (cnt > BCAP) cnt = BCAP;
    for (int i = t; i < cnt; i += 256) {
        ldst[i] = sdst[e0 + i] - n0;   // 0..127
        lsrc[i] = ssrc[e0 + i];
    }
    if (t < 128) lhist[t] = 0;
    __syncthreads();
    for (int i = t; i < cnt; i += 256) atomicAdd(&lhist[ldst[i]], 1);
    __syncthreads();
    if (t < 128) loff[t] = lhist[t];
    __syncthreads();
    for (int off = 1; off < 128; off <<= 1) {   // Hillis-Steele inclusive scan
        int v = 0;
        if (t < 128) { v = loff[t]; if (t >= off) v += loff[t - off]; }
        __syncthreads();
        if (t < 128) loff[t] = v;
        __syncthreads();
    }
    if (t < 128) {
        int excl = loff[t] - lhist[t];
        lcur[t] = excl;
        int n = n0 + t;
        if (n < N_NODES) {
            offsets[n] = e0 + excl;
            dis[n] = rsqrtf((float)lhist[t] + 1.0f);
        }
    }
    if (b == 0 && t == 0) offsets[N_NODES] = N_EDGES;
    __syncthreads();
    for (int i = t; i < cnt; i += 256) {
        int pos = atomicAdd(&lcur[ldst[i]], 1);
        csr_src[e0 + pos] = lsrc[i];
    }
}

// ---------------- pack W[K x 256] fp32 -> split bf16 planes in MFMA B-frag layout ----------
template<int K>
__global__ void pack_w_kernel(const float* __restrict__ W,
                              unsigned short* __restrict__ hi,
                              unsigned short* __restrict__ lo) {
    constexpr int KS = K / 32;
    int idx = blockIdx.x * blockDim.x + threadIdx.x;
    if (idx >= 16 * KS * 64) return;
    int l = idx & 63;
    int s = (idx >> 6) % KS;
    int t = idx / (64 * KS);
    int k0 = s * 32 + (l >> 4) * 8;
    int n  = t * 16 + (l & 15);
    size_t base = (size_t)idx * 8;
#pragma unroll
    for (int j = 0; j < 8; ++j) {
        float w = W[(size_t)(k0 + j) * 256 + n];
        unsigned short h = f2bf(w);
        float rem = w - bf2f(h);
        hi[base + j] = h;
        lo[base + j] = f2bf(rem);
    }
}

// ---------------- GEMM1: x[M×37] @ W1[37×128], out bf16 = acc * dis[row] ----------------
__global__ __launch_bounds__(128, 2)
void gemm1_kernel(const float* __restrict__ x, const float* __restrict__ W,
                  const float* __restrict__ dis, unsigned short* __restrict__ out) {
    __shared__ float lds[16 * 37];
    int row0 = blockIdx.x * 16;
    int t = threadIdx.x;   // 0..127 (= col)
    const float* src = x + (size_t)row0 * 37;
    for (int i = t; i < 16 * 37; i += 128) lds[i] = src[i];
    __syncthreads();
    float acc[16];
#pragma unroll
    for (int r = 0; r < 16; ++r) acc[r] = 0.0f;
#pragma unroll
    for (int k = 0; k < 37; ++k) {
        float wv = W[k * 128 + t];
#pragma unroll
        for (int r = 0; r < 16; ++r) acc[r] += lds[r * 37 + k] * wv;
    }
#pragma unroll
    for (int r = 0; r < 16; ++r) {
        int row = row0 + r;
        out[(size_t)row * 128 + t] = f2bf(acc[r] * dis[row]);
    }
}

// ---------------- aggregation over bf16 table (uniform index loads, 8-wide MLP) ----------
template<int F, bool FINISH>
__global__ __launch_bounds__(256, 4)
void agg_bf16_kernel(const unsigned short* __restrict__ tab,
                     const int* __restrict__ csr_src,
                     const int* __restrict__ offsets,
                     const float* __restrict__ dis,
                     const float* __restrict__ bias,
                     unsigned short* __restrict__ out) {
    int wave = threadIdx.x >> 6;
    int lane = threadIdx.x & 63;
    int n = blockIdx.x * 4 + wave;

    float acc[F / 64];
    if (F == 128) {
        ushort2 u = ((const ushort2*)(tab + (size_t)n * F))[lane];
        acc[0] = bf2f(u.x); acc[1] = bf2f(u.y);
    } else {
        ushort4 u = ((const ushort4*)(tab + (size_t)n * F))[lane];
        acc[0] = bf2f(u.x); acc[1] = bf2f(u.y); acc[2] = bf2f(u.z); acc[3] = bf2f(u.w);
    }

    int lo = offsets[n], hi = offsets[n + 1];
    int j = lo;
    for (; j + 8 <= hi; j += 8) {
        int s0 = csr_src[j + 0], s1 = csr_src[j + 1], s2 = csr_src[j + 2], s3 = csr_src[j + 3];
        int s4 = csr_src[j + 4], s5 = csr_src[j + 5], s6 = csr_src[j + 6], s7 = csr_src[j + 7];
        if (F == 128) {
            ushort2 u0 = ((const ushort2*)(tab + (size_t)s0 * F))[lane];
            ushort2 u1 = ((const ushort2*)(tab + (size_t)s1 * F))[lane];
            ushort2 u2 = ((const ushort2*)(tab + (size_t)s2 * F))[lane];
            ushort2 u3 = ((const ushort2*)(tab + (size_t)s3 * F))[lane];
            ushort2 u4 = ((const ushort2*)(tab + (size_t)s4 * F))[lane];
            ushort2 u5 = ((const ushort2*)(tab + (size_t)s5 * F))[lane];
            ushort2 u6 = ((const ushort2*)(tab + (size_t)s6 * F))[lane];
            ushort2 u7 = ((const ushort2*)(tab + (size_t)s7 * F))[lane];
            acc[0] += ((bf2f(u0.x) + bf2f(u1.x)) + (bf2f(u2.x) + bf2f(u3.x)))
                    + ((bf2f(u4.x) + bf2f(u5.x)) + (bf2f(u6.x) + bf2f(u7.x)));
            acc[1] += ((bf2f(u0.y) + bf2f(u1.y)) + (bf2f(u2.y) + bf2f(u3.y)))
                    + ((bf2f(u4.y) + bf2f(u5.y)) + (bf2f(u6.y) + bf2f(u7.y)));
        } else {
            ushort4 u0 = ((const ushort4*)(tab + (size_t)s0 * F))[lane];
            ushort4 u1 = ((const ushort4*)(tab + (size_t)s1 * F))[lane];
            ushort4 u2 = ((const ushort4*)(tab + (size_t)s2 * F))[lane];
            ushort4 u3 = ((const ushort4*)(tab + (size_t)s3 * F))[lane];
            ushort4 u4 = ((const ushort4*)(tab + (size_t)s4 * F))[lane];
            ushort4 u5 = ((const ushort4*)(tab + (size_t)s5 * F))[lane];
            ushort4 u6 = ((const ushort4*)(tab + (size_t)s6 * F))[lane];
            ushort4 u7 = ((const ushort4*)(tab + (size_t)s7 * F))[lane];
            acc[0] += ((bf2f(u0.x) + bf2f(u1.x)) + (bf2f(u2.x) + bf2f(u3.x)))
                    + ((bf2f(u4.x) + bf2f(u5.x)) + (bf2f(u6.x) + bf2f(u7.x)));
            acc[1] += ((bf2f(u0.y) + bf2f(u1.y)) + (bf2f(u2.y) + bf2f(u3.y)))
                    + ((bf2f(u4.y) + bf2f(u5.y)) + (bf2f(u6.y) + bf2f(u7.y)));
            acc[2] += ((bf2f(u0.z) + bf2f(u1.z)) + (bf2f(u2.z) + bf2f(u3.z)))
                    + ((bf2f(u4.z) + bf2f(u5.z)) + (bf2f(u6.z) + bf2f(u7.z)));
            acc[3] += ((bf2f(u0.w) + bf2f(u1.w)) + (bf2f(u2.w) + bf2f(u3.w)))
                    + ((bf2f(u4.w) + bf2f(u5.w)) + (bf2f(u6.w) + bf2f(u7.w)));
        }
    }
    for (; j < hi; ++j) {
        int s = csr_src[j];
        if (F == 128) {
            ushort2 u = ((const ushort2*)(tab + (size_t)s * F))[lane];
            acc[0] += bf2f(u.x); acc[1] += bf2f(u.y);
        } else {
            ushort4 u = ((const ushort4*)(tab + (size_t)s * F))[lane];
            acc[0] += bf2f(u.x); acc[1] += bf2f(u.y); acc[2] += bf2f(u.z); acc[3] += bf2f(u.w);
        }
    }

    float d = dis[n];
    if (F == 128) {
        ushort2 o;
        if (FINISH) {
            o.x = f2bf(fmaxf(d * acc[0] + bias[lane * 2 + 0], 0.0f) * d);
            o.y = f2bf(fmaxf(d * acc[1] + bias[lane * 2 + 1], 0.0f) * d);
        } else {
            o.x = f2bf(d * acc[0]); o.y = f2bf(d * acc[1]);
        }
        ((ushort2*)(out + (size_t)n * F))[lane] = o;
    } else {
        ushort4 o;
        if (FINISH) {
            o.x = f2bf(fmaxf(d * acc[0] + bias[lane * 4 + 0], 0.0f) * d);
            o.y = f2bf(fmaxf(d * acc[1] + bias[lane * 4 + 1], 0.0f) * d);
            o.z = f2bf(fmaxf(d * acc[2] + bias[lane * 4 + 2], 0.0f) * d);
            o.w = f2bf(fmaxf(d * acc[3] + bias[lane * 4 + 3], 0.0f) * d);
        } else {
            o.x = f2bf(d * acc[0]); o.y = f2bf(d * acc[1]);
            o.z = f2bf(d * acc[2]); o.w = f2bf(d * acc[3]);
        }
        ((ushort4*)(out + (size_t)n * F))[lane] = o;
    }
}

// ---------------- MFMA GEMM: A bf16 [M×K] @ (Whi+Wlo) [K×256] + bias, relu ---------------
template<int K, bool TO_TABLE>
__global__ __launch_bounds__(256, 4)
void mfma_gemm_kernel(const unsigned short* __restrict__ A,
                      const unsigned short* __restrict__ Bhi,
                      const unsigned short* __restrict__ Blo,
                      const float* __restrict__ bias,
                      const float* __restrict__ dis,
                      void* __restrict__ outv) {
    constexpr int KS = K / 32;
    int l   = threadIdx.x & 63;
    int wid = threadIdx.x >> 6;      // 0..3
    int n0  = wid * 64;
    int m0  = blockIdx.x * 32;

    f32x4 acc0[4], acc1[4];
#pragma unroll
    for (int tn = 0; tn < 4; ++tn) { acc0[tn] = (f32x4){0,0,0,0}; acc1[tn] = (f32x4){0,0,0,0}; }

    const unsigned short* a0 = A + (size_t)(m0 + (l & 15)) * K + (l >> 4) * 8;
    const unsigned short* a1 = a0 + (size_t)16 * K;

#pragma unroll
    for (int s = 0; s < KS; ++s) {
        bf16x8 af0 = *(const bf16x8*)(a0 + s * 32);
        bf16x8 af1 = *(const bf16x8*)(a1 + s * 32);
#pragma unroll
        for (int tn = 0; tn < 4; ++tn) {
            int t = (n0 >> 4) + tn;
            size_t boff = ((size_t)(t * KS + s) * 64 + l) * 8;
            bf16x8 bh = *(const bf16x8*)(Bhi + boff);
            bf16x8 bl = *(const bf16x8*)(Blo + boff);
            acc0[tn] = __builtin_amdgcn_mfma_f32_16x16x32_bf16(af0, bh, acc0[tn], 0, 0, 0);
            acc0[tn] = __builtin_amdgcn_mfma_f32_16x16x32_bf16(af0, bl, acc0[tn], 0, 0, 0);
            acc1[tn] = __builtin_amdgcn_mfma_f32_16x16x32_bf16(af1, bh, acc1[tn], 0, 0, 0);
            acc1[tn] = __builtin_amdgcn_mfma_f32_16x16x32_bf16(af1, bl, acc1[tn], 0, 0, 0);
        }
    }

    int rowg = (l >> 4) * 4;
#pragma unroll
    for (int tn = 0; tn < 4; ++tn) {
        int n = n0 + tn * 16 + (l & 15);
        float b = bias[n];
#pragma unroll
        for (int r = 0; r < 4; ++r) {
            {
                int m = m0 + rowg + r;
                float v = fmaxf(acc0[tn][r] + b, 0.0f);
                if (TO_TABLE) ((unsigned short*)outv)[(size_t)m * 256 + n] = f2bf(v * dis[m]);
                else          ((float*)outv)[(size_t)m * 256 + n] = v;
            }
            {
                int m = m0 + 16 + rowg + r;
                float v = fmaxf(acc1[tn][r] + b, 0.0f);
                if (TO_TABLE) ((unsigned short*)outv)[(size_t)m * 256 + n] = f2bf(v * dis[m]);
                else          ((float*)outv)[(size_t)m * 256 + n] = v;
            }
        }
    }
}

// ---------------- pooling ----------------
__device__ __forceinline__ int lower_bound_dev(const int* __restrict__ a, int n, int key) {
    int lo = 0, hi = n;
    while (lo < hi) {
        int mid = (lo + hi) >> 1;
        if (a[mid] < key) lo = mid + 1; else hi = mid;
    }
    return lo;
}

__global__ __launch_bounds__(256, 4)
void pool_kernel(const float* __restrict__ h, const int* __restrict__ batch,
                 float* __restrict__ pooled, int nNodes) {
    int g = blockIdx.x;
    int t = threadIdx.x; // 0..255
    __shared__ int bounds[2];
    if (t == 0) bounds[0] = lower_bound_dev(batch, nNodes, g);
    if (t == 1) bounds[1] = lower_bound_dev(batch, nNodes, g + 1);
    __syncthreads();
    int lo = bounds[0], hi = bounds[1];
    float acc = 0.0f;
    for (int n = lo; n < hi; ++n) acc += h[(size_t)n * 256 + t];
    float cnt = (float)(hi - lo);
    pooled[(size_t)g * 256 + t] = acc / fmaxf(cnt, 1.0f);
}

// ---------------- head GEMM (fp32 naive, tiny M) ----------------
__global__ __launch_bounds__(256, 2)
void head_gemm_kernel(const float* __restrict__ H, const float* __restrict__ W,
                      const float* __restrict__ bias, float* __restrict__ out) {
    __shared__ float lds[16 * 256];
    int row0 = blockIdx.x * 16;
    int t = threadIdx.x;   // 0..255 (= col)
    const float* src = H + (size_t)row0 * 256;
    for (int i = t; i < 16 * 256; i += 256) lds[i] = src[i];
    __syncthreads();
    float acc[16];
#pragma unroll
    for (int r = 0; r < 16; ++r) acc[r] = 0.0f;
#pragma unroll 4
    for (int k = 0; k < 256; ++k) {
        float wv = W[k * 256 + t];
#pragma unroll
        for (int r = 0; r < 16; ++r) acc[r] += lds[r * 256 + k] * wv;
    }
#pragma unroll
    for (int r = 0; r < 16; ++r)
        out[(size_t)(row0 + r) * 256 + t] = acc[r] + bias[t];
}

// ---------------- launch ----------------
static inline size_t align_up(size_t x, size_t a) { return (x + a - 1) & ~(a - 1); }

extern "C" void kernel_launch(void* const* d_in, const int* in_sizes, int n_in,
                              void* d_out, int out_size, void* d_ws, size_t ws_size,
                              hipStream_t stream) {
    const float* x  = (const float*)d_in[0];
    const float* W1 = (const float*)d_in[1];
    const float* b1 = (const float*)d_in[2];
    const float* W2 = (const float*)d_in[3];
    const float* b2 = (const float*)d_in[4];
    const float* W3 = (const float*)d_in[5];
    const float* b3 = (const float*)d_in[6];
    const float* Wp = (const float*)d_in[7];
    const float* bp = (const float*)d_in[8];
    const int*   ei = (const int*)d_in[9];   // [2, E]
    const int*   batch = (const int*)d_in[10];
    float* out = (float*)d_out;

    const int* e_src = ei;
    const int* e_dst = ei + N_EDGES;

    char* p = (char*)d_ws;
    size_t off = 0;
    auto take = [&](size_t bytes) {
        void* r = p + off;
        off = align_up(off + bytes, 256);
        return r;
    };
    int*   hist        = (int*)  take(sizeof(int) * NB * NBLK);
    int*   tot         = (int*)  take(sizeof(int) * NB);
    int*   bucketStart = (int*)  take(sizeof(int) * (NB + 1));
    int*   offsets     = (int*)  take(sizeof(int) * (N_NODES + 1));
    int*   csr_src     = (int*)  take(sizeof(int) * N_EDGES);
    float* dis         = (float*)take(sizeof(float) * N_NODES);
    float* pooled      = (float*)take(sizeof(float) * N_GRAPHS * 256);
    unsigned short* whi2 = (unsigned short*)take(sizeof(unsigned short) * 128 * 256);
    unsigned short* wlo2 = (unsigned short*)take(sizeof(unsigned short) * 128 * 256);
    unsigned short* whi3 = (unsigned short*)take(sizeof(unsigned short) * 256 * 256);
    unsigned short* wlo3 = (unsigned short*)take(sizeof(unsigned short) * 256 * 256);
    unsigned short* bufX = (unsigned short*)take(sizeof(unsigned short) * (size_t)N_NODES * 256);
    unsigned short* bufY = (unsigned short*)take(sizeof(unsigned short) * (size_t)N_NODES * 256);
    float* h3          = (float*)take(sizeof(float) * (size_t)N_NODES * 256);

    // CSR-build scratch aliases h3 (consumed before h3 is written)
    int* sdst = (int*)h3;
    int* ssrc = sdst + N_EDGES;

    unsigned short* t1     = bufX;                               // [100K×128]
    unsigned short* table2 = bufX + (size_t)N_NODES * 128;       // [100K×128]
    unsigned short* pbuf2  = bufX;                               // overwrite t1
    unsigned short* table3 = bufY;                               // [100K×256]
    unsigned short* pbuf3  = bufX;                               // [100K×256] full X

    // ---- CSR build via counting sort (no global atomics) ----
    hist_kernel<<<NBLK, 256, 0, stream>>>(e_dst, hist);
    bucket_tot_kernel<<<NB, 64, 0, stream>>>(hist, tot);
    bucket_scan_kernel<<<1, 256, 0, stream>>>(tot, bucketStart);
    bucket_base_kernel<<<(NB + 255) / 256, 256, 0, stream>>>(hist, bucketStart);
    scatter1_kernel<<<NBLK, 256, 0, stream>>>(e_src, e_dst, hist, sdst, ssrc);
    csr2_kernel<<<NB, 256, 0, stream>>>(sdst, ssrc, bucketStart, offsets, dis, csr_src);

    // pack W2/W3 into MFMA B-frag split-bf16 planes
    pack_w_kernel<128><<<(16 * 4 * 64 + 255) / 256, 256, 0, stream>>>(W2, whi2, wlo2);
    pack_w_kernel<256><<<(16 * 8 * 64 + 255) / 256, 256, 0, stream>>>(W3, whi3, wlo3);

    // Layer 1 (GEMM-first): t1 = bf16((x@W1)*dis)
    gemm1_kernel<<<N_NODES / 16, 128, 0, stream>>>(x, W1, dis, t1);
    agg_bf16_kernel<128, true><<<N_NODES / 4, 256, 0, stream>>>(t1, csr_src, offsets, dis, b1, table2);

    // Layer 2 (propagate-first)
    agg_bf16_kernel<128, false><<<N_NODES / 4, 256, 0, stream>>>(table2, csr_src, offsets, dis, nullptr, pbuf2);
    mfma_gemm_kernel<128, true><<<N_NODES / 32, 256, 0, stream>>>(pbuf2, whi2, wlo2, b2, dis, table3);

    // Layer 3 (propagate-first)
    agg_bf16_kernel<256, false><<<N_NODES / 4, 256, 0, stream>>>(table3, csr_src, offsets, dis, nullptr, pbuf3);
    mfma_gemm_kernel<256, false><<<N_NODES / 32, 256, 0, stream>>>(pbuf3, whi3, wlo3, b3, nullptr, h3);

    // pool + head
    pool_kernel<<<N_GRAPHS, 256, 0, stream>>>(h3, batch, pooled, N_NODES);
    head_gemm_kernel<<<N_GRAPHS / 16, 256, 0, stream>>>(pooled, Wp, bp, out);
}

// Round 6
// 737.807 us; speedup vs baseline: 16.2393x; 1.1076x over previous
//
#include <hip/hip_runtime.h>

#define N_NODES  100000
#define N_EDGES  3200000
#define N_GRAPHS 3200

// CSR-build constants
#define NBLK 200            // edge-chunk blocks
#define EB   16000          // edges per chunk (NBLK*EB == N_EDGES)
#define BSH  7              // bucket = dst >> 7  (128 nodes/bucket)
#define NB   ((N_NODES + 127) >> BSH)   // 782 buckets
#define BCAP 5120           // max edges per bucket staged in LDS (mean 4096, sigma 64)

typedef __attribute__((ext_vector_type(8))) short bf16x8;
typedef __attribute__((ext_vector_type(4))) float f32x4;

// ---------------- bf16 helpers ----------------
__device__ __forceinline__ float bf2f(unsigned short u) {
    return __uint_as_float(((unsigned)u) << 16);
}
__device__ __forceinline__ unsigned short f2bf(float f) {
    unsigned u = __float_as_uint(f);
    u += 0x7fffu + ((u >> 16) & 1u);   // RNE
    return (unsigned short)(u >> 16);
}

// ================= CSR build (counting sort, no global atomics) =================

__global__ __launch_bounds__(256, 4)
void hist_kernel(const int* __restrict__ dst, int* __restrict__ hist) {
    __shared__ int lh[NB];
    int blk = blockIdx.x, t = threadIdx.x;
    for (int b = t; b < NB; b += 256) lh[b] = 0;
    __syncthreads();
    int e0 = blk * EB;
    for (int i = t; i < EB; i += 256)
        atomicAdd(&lh[dst[e0 + i] >> BSH], 1);
    __syncthreads();
    for (int b = t; b < NB; b += 256) hist[b * NBLK + blk] = lh[b];
}

__global__ void bucket_tot_kernel(const int* __restrict__ hist, int* __restrict__ tot) {
    int b = blockIdx.x, l = threadIdx.x;   // 64 threads
    int s = 0;
    for (int k = l; k < NBLK; k += 64) s += hist[b * NBLK + k];
    for (int off = 32; off; off >>= 1) s += __shfl_down(s, off);
    if (l == 0) tot[b] = s;
}

__global__ void bucket_scan_kernel(const int* __restrict__ tot, int* __restrict__ bucketStart) {
    __shared__ int part[256];
    int t = threadIdx.x;
    int chunk = (NB + 255) / 256;
    int lo = t * chunk; if (lo > NB) lo = NB;
    int hi = lo + chunk; if (hi > NB) hi = NB;
    int s = 0;
    for (int i = lo; i < hi; ++i) s += tot[i];
    part[t] = s;
    __syncthreads();
    for (int off = 1; off < 256; off <<= 1) {
        int v = part[t];
        int a = (t >= off) ? part[t - off] : 0;
        __syncthreads();
        part[t] = v + a;
        __syncthreads();
    }
    int run = (t == 0) ? 0 : part[t - 1];
    for (int i = lo; i < hi; ++i) { bucketStart[i] = run; run += tot[i]; }
    if (t == 255) bucketStart[NB] = run;
}

__global__ void bucket_base_kernel(int* __restrict__ hist, const int* __restrict__ bucketStart) {
    int b = blockIdx.x * blockDim.x + threadIdx.x;
    if (b >= NB) return;
    int run = bucketStart[b];
    int* row = hist + b * NBLK;
#pragma unroll 4
    for (int k = 0; k < NBLK; ++k) { int v = row[k]; row[k] = run; run += v; }
}

__global__ __launch_bounds__(256, 4)
void scatter1_kernel(const int* __restrict__ src, const int* __restrict__ dst,
                     const int* __restrict__ base,
                     int* __restrict__ sdst, int* __restrict__ ssrc) {
    __shared__ int lcur[NB];
    int blk = blockIdx.x, t = threadIdx.x;
    for (int b = t; b < NB; b += 256) lcur[b] = base[b * NBLK + blk];
    __syncthreads();
    int e0 = blk * EB;
    for (int i = t; i < EB; i += 256) {
        int d = dst[e0 + i], s = src[e0 + i];
        int pos = atomicAdd(&lcur[d >> BSH], 1);
        sdst[pos] = d;
        ssrc[pos] = s;
    }
}

__global__ __launch_bounds__(256, 1)
void csr2_kernel(const int* __restrict__ sdst, const int* __restrict__ ssrc,
                 const int* __restrict__ bucketStart,
                 int* __restrict__ offsets, float* __restrict__ dis,
                 int* __restrict__ csr_src) {
    __shared__ int ldst[BCAP];
    __shared__ int lsrc[BCAP];
    __shared__ int lhist[128], loff[128], lcur[128];
    int b = blockIdx.x, t = threadIdx.x;
    int n0 = b << BSH;
    int e0 = bucketStart[b], e1 = bucketStart[b + 1];
    int cnt = e1 - e0; if (cnt > BCAP) cnt = BCAP;
    for (int i = t; i < cnt; i += 256) {
        ldst[i] = sdst[e0 + i] - n0;   // 0..127
        lsrc[i] = ssrc[e0 + i];
    }
    if (t < 128) lhist[t] = 0;
    __syncthreads();
    for (int i = t; i < cnt; i += 256) atomicAdd(&lhist[ldst[i]], 1);
    __syncthreads();
    if (t < 128) loff[t] = lhist[t];
    __syncthreads();
    for (int off = 1; off < 128; off <<= 1) {   // Hillis-Steele inclusive scan
        int v = 0;
        if (t < 128) { v = loff[t]; if (t >= off) v += loff[t - off]; }
        __syncthreads();
        if (t < 128) loff[t] = v;
        __syncthreads();
    }
    if (t < 128) {
        int excl = loff[t] - lhist[t];
        lcur[t] = excl;
        int n = n0 + t;
        if (n < N_NODES) {
            offsets[n] = e0 + excl;
            dis[n] = rsqrtf((float)lhist[t] + 1.0f);
        }
    }
    if (b == 0 && t == 0) offsets[N_NODES] = N_EDGES;
    __syncthreads();
    for (int i = t; i < cnt; i += 256) {
        int pos = atomicAdd(&lcur[ldst[i]], 1);
        csr_src[e0 + pos] = lsrc[i];
    }
}

// ---------------- pack W[K x 256] fp32 -> split bf16 planes in MFMA B-frag layout ----------
template<int K>
__global__ void pack_w_kernel(const float* __restrict__ W,
                              unsigned short* __restrict__ hi,
                              unsigned short* __restrict__ lo) {
    constexpr int KS = K / 32;
    int idx = blockIdx.x * blockDim.x + threadIdx.x;
    if (idx >= 16 * KS * 64) return;
    int l = idx & 63;
    int s = (idx >> 6) % KS;
    int t = idx / (64 * KS);
    int k0 = s * 32 + (l >> 4) * 8;
    int n  = t * 16 + (l & 15);
    size_t base = (size_t)idx * 8;
#pragma unroll
    for (int j = 0; j < 8; ++j) {
        float w = W[(size_t)(k0 + j) * 256 + n];
        unsigned short h = f2bf(w);
        float rem = w - bf2f(h);
        hi[base + j] = h;
        lo[base + j] = f2bf(rem);
    }
}

// ---------------- GEMM1: x[M×37] @ W1[37×128], out bf16 = acc * dis[row] ----------------
__global__ __launch_bounds__(128, 2)
void gemm1_kernel(const float* __restrict__ x, const float* __restrict__ W,
                  const float* __restrict__ dis, unsigned short* __restrict__ out) {
    __shared__ float lds[16 * 37];
    int row0 = blockIdx.x * 16;
    int t = threadIdx.x;   // 0..127 (= col)
    const float* src = x + (size_t)row0 * 37;
    for (int i = t; i < 16 * 37; i += 128) lds[i] = src[i];
    __syncthreads();
    float acc[16];
#pragma unroll
    for (int r = 0; r < 16; ++r) acc[r] = 0.0f;
#pragma unroll
    for (int k = 0; k < 37; ++k) {
        float wv = W[k * 128 + t];
#pragma unroll
        for (int r = 0; r < 16; ++r) acc[r] += lds[r * 37 + k] * wv;
    }
#pragma unroll
    for (int r = 0; r < 16; ++r) {
        int row = row0 + r;
        out[(size_t)row * 128 + t] = f2bf(acc[r] * dis[row]);
    }
}

// ---------------- aggregation over bf16 table (16-deep MLP) ----------
template<int F, bool FINISH>
__global__ __launch_bounds__(256, 4)
void agg_bf16_kernel(const unsigned short* __restrict__ tab,
                     const int* __restrict__ csr_src,
                     const int* __restrict__ offsets,
                     const float* __restrict__ dis,
                     const float* __restrict__ bias,
                     unsigned short* __restrict__ out) {
    int wave = threadIdx.x >> 6;
    int lane = threadIdx.x & 63;
    int n = blockIdx.x * 4 + wave;

    float acc[F / 64];
    if (F == 128) {
        ushort2 u = ((const ushort2*)(tab + (size_t)n * F))[lane];
        acc[0] = bf2f(u.x); acc[1] = bf2f(u.y);
    } else {
        ushort4 u = ((const ushort4*)(tab + (size_t)n * F))[lane];
        acc[0] = bf2f(u.x); acc[1] = bf2f(u.y); acc[2] = bf2f(u.z); acc[3] = bf2f(u.w);
    }

    int lo = offsets[n], hi = offsets[n + 1];
    int j = lo;
    // 16-deep: 16 independent row-loads in flight per wave
    for (; j + 16 <= hi; j += 16) {
        int sidx[16];
#pragma unroll
        for (int u = 0; u < 16; ++u) sidx[u] = csr_src[j + u];
        if (F == 128) {
            ushort2 v[16];
#pragma unroll
            for (int u = 0; u < 16; ++u)
                v[u] = ((const ushort2*)(tab + (size_t)sidx[u] * F))[lane];
#pragma unroll
            for (int u = 0; u < 16; ++u) { acc[0] += bf2f(v[u].x); acc[1] += bf2f(v[u].y); }
        } else {
            ushort4 v[16];
#pragma unroll
            for (int u = 0; u < 16; ++u)
                v[u] = ((const ushort4*)(tab + (size_t)sidx[u] * F))[lane];
#pragma unroll
            for (int u = 0; u < 16; ++u) {
                acc[0] += bf2f(v[u].x); acc[1] += bf2f(v[u].y);
                acc[2] += bf2f(v[u].z); acc[3] += bf2f(v[u].w);
            }
        }
    }
    for (; j + 4 <= hi; j += 4) {
        int sidx[4];
#pragma unroll
        for (int u = 0; u < 4; ++u) sidx[u] = csr_src[j + u];
        if (F == 128) {
            ushort2 v[4];
#pragma unroll
            for (int u = 0; u < 4; ++u)
                v[u] = ((const ushort2*)(tab + (size_t)sidx[u] * F))[lane];
#pragma unroll
            for (int u = 0; u < 4; ++u) { acc[0] += bf2f(v[u].x); acc[1] += bf2f(v[u].y); }
        } else {
            ushort4 v[4];
#pragma unroll
            for (int u = 0; u < 4; ++u)
                v[u] = ((const ushort4*)(tab + (size_t)sidx[u] * F))[lane];
#pragma unroll
            for (int u = 0; u < 4; ++u) {
                acc[0] += bf2f(v[u].x); acc[1] += bf2f(v[u].y);
                acc[2] += bf2f(v[u].z); acc[3] += bf2f(v[u].w);
            }
        }
    }
    for (; j < hi; ++j) {
        int s = csr_src[j];
        if (F == 128) {
            ushort2 u = ((const ushort2*)(tab + (size_t)s * F))[lane];
            acc[0] += bf2f(u.x); acc[1] += bf2f(u.y);
        } else {
            ushort4 u = ((const ushort4*)(tab + (size_t)s * F))[lane];
            acc[0] += bf2f(u.x); acc[1] += bf2f(u.y); acc[2] += bf2f(u.z); acc[3] += bf2f(u.w);
        }
    }

    float d = dis[n];
    if (F == 128) {
        ushort2 o;
        if (FINISH) {
            o.x = f2bf(fmaxf(d * acc[0] + bias[lane * 2 + 0], 0.0f) * d);
            o.y = f2bf(fmaxf(d * acc[1] + bias[lane * 2 + 1], 0.0f) * d);
        } else {
            o.x = f2bf(d * acc[0]); o.y = f2bf(d * acc[1]);
        }
        ((ushort2*)(out + (size_t)n * F))[lane] = o;
    } else {
        ushort4 o;
        if (FINISH) {
            o.x = f2bf(fmaxf(d * acc[0] + bias[lane * 4 + 0], 0.0f) * d);
            o.y = f2bf(fmaxf(d * acc[1] + bias[lane * 4 + 1], 0.0f) * d);
            o.z = f2bf(fmaxf(d * acc[2] + bias[lane * 4 + 2], 0.0f) * d);
            o.w = f2bf(fmaxf(d * acc[3] + bias[lane * 4 + 3], 0.0f) * d);
        } else {
            o.x = f2bf(d * acc[0]); o.y = f2bf(d * acc[1]);
            o.z = f2bf(d * acc[2]); o.w = f2bf(d * acc[3]);
        }
        ((ushort4*)(out + (size_t)n * F))[lane] = o;
    }
}

// ---------------- MFMA GEMM: A bf16 [M×K] @ (Whi+Wlo) [K×256] + bias, relu ---------------
// MODE 0: out fp32 = relu(acc+b)
// MODE 1: out bf16 = bf16(relu(acc+b) * dis[row])   (next gather table)
// MODE 2: out bf16 = bf16(relu(acc+b))
template<int K, int MODE>
__global__ __launch_bounds__(256, 4)
void mfma_gemm_kernel(const unsigned short* __restrict__ A,
                      const unsigned short* __restrict__ Bhi,
                      const unsigned short* __restrict__ Blo,
                      const float* __restrict__ bias,
                      const float* __restrict__ dis,
                      void* __restrict__ outv) {
    constexpr int KS = K / 32;
    int l   = threadIdx.x & 63;
    int wid = threadIdx.x >> 6;      // 0..3
    int n0  = wid * 64;
    int m0  = blockIdx.x * 32;

    f32x4 acc0[4], acc1[4];
#pragma unroll
    for (int tn = 0; tn < 4; ++tn) { acc0[tn] = (f32x4){0,0,0,0}; acc1[tn] = (f32x4){0,0,0,0}; }

    const unsigned short* a0 = A + (size_t)(m0 + (l & 15)) * K + (l >> 4) * 8;
    const unsigned short* a1 = a0 + (size_t)16 * K;

#pragma unroll
    for (int s = 0; s < KS; ++s) {
        bf16x8 af0 = *(const bf16x8*)(a0 + s * 32);
        bf16x8 af1 = *(const bf16x8*)(a1 + s * 32);
#pragma unroll
        for (int tn = 0; tn < 4; ++tn) {
            int t = (n0 >> 4) + tn;
            size_t boff = ((size_t)(t * KS + s) * 64 + l) * 8;
            bf16x8 bh = *(const bf16x8*)(Bhi + boff);
            bf16x8 bl = *(const bf16x8*)(Blo + boff);
            acc0[tn] = __builtin_amdgcn_mfma_f32_16x16x32_bf16(af0, bh, acc0[tn], 0, 0, 0);
            acc0[tn] = __builtin_amdgcn_mfma_f32_16x16x32_bf16(af0, bl, acc0[tn], 0, 0, 0);
            acc1[tn] = __builtin_amdgcn_mfma_f32_16x16x32_bf16(af1, bh, acc1[tn], 0, 0, 0);
            acc1[tn] = __builtin_amdgcn_mfma_f32_16x16x32_bf16(af1, bl, acc1[tn], 0, 0, 0);
        }
    }

    int rowg = (l >> 4) * 4;
#pragma unroll
    for (int tn = 0; tn < 4; ++tn) {
        int n = n0 + tn * 16 + (l & 15);
        float b = bias[n];
#pragma unroll
        for (int r = 0; r < 4; ++r) {
#pragma unroll
            for (int half = 0; half < 2; ++half) {
                int m = m0 + half * 16 + rowg + r;
                float v = fmaxf((half ? acc1[tn][r] : acc0[tn][r]) + b, 0.0f);
                if (MODE == 1)      ((unsigned short*)outv)[(size_t)m * 256 + n] = f2bf(v * dis[m]);
                else if (MODE == 2) ((unsigned short*)outv)[(size_t)m * 256 + n] = f2bf(v);
                else                ((float*)outv)[(size_t)m * 256 + n] = v;
            }
        }
    }
}

// ---------------- pooling (bf16 input, wave per graph) ----------------
__device__ __forceinline__ int lower_bound_dev(const int* __restrict__ a, int n, int key) {
    int lo = 0, hi = n;
    while (lo < hi) {
        int mid = (lo + hi) >> 1;
        if (a[mid] < key) lo = mid + 1; else hi = mid;
    }
    return lo;
}

__global__ __launch_bounds__(256, 4)
void pool_bf16_kernel(const unsigned short* __restrict__ h, const int* __restrict__ batch,
                      float* __restrict__ pooled) {
    int wave = threadIdx.x >> 6;
    int lane = threadIdx.x & 63;
    int g = blockIdx.x * 4 + wave;
    int lo = lower_bound_dev(batch, N_NODES, g);
    int hi = lower_bound_dev(batch, N_NODES, g + 1);
    float a0 = 0, a1 = 0, a2 = 0, a3 = 0;
    for (int n = lo; n < hi; ++n) {
        ushort4 u = ((const ushort4*)(h + (size_t)n * 256))[lane];
        a0 += bf2f(u.x); a1 += bf2f(u.y); a2 += bf2f(u.z); a3 += bf2f(u.w);
    }
    float inv = 1.0f / fmaxf((float)(hi - lo), 1.0f);
    float4 o = {a0 * inv, a1 * inv, a2 * inv, a3 * inv};
    *(float4*)&pooled[(size_t)g * 256 + lane * 4] = o;
}

// ---------------- head GEMM (fp32 naive, tiny M) ----------------
__global__ __launch_bounds__(256, 2)
void head_gemm_kernel(const float* __restrict__ H, const float* __restrict__ W,
                      const float* __restrict__ bias, float* __restrict__ out) {
    __shared__ float lds[16 * 256];
    int row0 = blockIdx.x * 16;
    int t = threadIdx.x;   // 0..255 (= col)
    const float* src = H + (size_t)row0 * 256;
    for (int i = t; i < 16 * 256; i += 256) lds[i] = src[i];
    __syncthreads();
    float acc[16];
#pragma unroll
    for (int r = 0; r < 16; ++r) acc[r] = 0.0f;
#pragma unroll 4
    for (int k = 0; k < 256; ++k) {
        float wv = W[k * 256 + t];
#pragma unroll
        for (int r = 0; r < 16; ++r) acc[r] += lds[r * 256 + k] * wv;
    }
#pragma unroll
    for (int r = 0; r < 16; ++r)
        out[(size_t)(row0 + r) * 256 + t] = acc[r] + bias[t];
}

// ---------------- launch ----------------
static inline size_t align_up(size_t x, size_t a) { return (x + a - 1) & ~(a - 1); }

extern "C" void kernel_launch(void* const* d_in, const int* in_sizes, int n_in,
                              void* d_out, int out_size, void* d_ws, size_t ws_size,
                              hipStream_t stream) {
    const float* x  = (const float*)d_in[0];
    const float* W1 = (const float*)d_in[1];
    const float* b1 = (const float*)d_in[2];
    const float* W2 = (const float*)d_in[3];
    const float* b2 = (const float*)d_in[4];
    const float* W3 = (const float*)d_in[5];
    const float* b3 = (const float*)d_in[6];
    const float* Wp = (const float*)d_in[7];
    const float* bp = (const float*)d_in[8];
    const int*   ei = (const int*)d_in[9];   // [2, E]
    const int*   batch = (const int*)d_in[10];
    float* out = (float*)d_out;

    const int* e_src = ei;
    const int* e_dst = ei + N_EDGES;

    char* p = (char*)d_ws;
    size_t off = 0;
    auto take = [&](size_t bytes) {
        void* r = p + off;
        off = align_up(off + bytes, 256);
        return r;
    };
    int*   hist        = (int*)  take(sizeof(int) * NB * NBLK);
    int*   tot         = (int*)  take(sizeof(int) * NB);
    int*   bucketStart = (int*)  take(sizeof(int) * (NB + 1));
    int*   offsets     = (int*)  take(sizeof(int) * (N_NODES + 1));
    int*   csr_src     = (int*)  take(sizeof(int) * N_EDGES);
    float* dis         = (float*)take(sizeof(float) * N_NODES);
    float* pooled      = (float*)take(sizeof(float) * N_GRAPHS * 256);
    unsigned short* whi2 = (unsigned short*)take(sizeof(unsigned short) * 128 * 256);
    unsigned short* wlo2 = (unsigned short*)take(sizeof(unsigned short) * 128 * 256);
    unsigned short* whi3 = (unsigned short*)take(sizeof(unsigned short) * 256 * 256);
    unsigned short* wlo3 = (unsigned short*)take(sizeof(unsigned short) * 256 * 256);
    unsigned short* bufX = (unsigned short*)take(sizeof(unsigned short) * (size_t)N_NODES * 256);
    unsigned short* bufY = (unsigned short*)take(sizeof(unsigned short) * (size_t)N_NODES * 256);
    unsigned short* h3   = (unsigned short*)take(sizeof(unsigned short) * (size_t)N_NODES * 256);

    // CSR-build scratch aliases h3 (consumed before h3 is written): needs 2*E ints = 25.6 MB <= 51.2 MB
    int* sdst = (int*)h3;
    int* ssrc = sdst + N_EDGES;

    unsigned short* t1     = bufX;                               // [100K×128]
    unsigned short* table2 = bufX + (size_t)N_NODES * 128;       // [100K×128]
    unsigned short* pbuf2  = bufX;                               // overwrite t1
    unsigned short* table3 = bufY;                               // [100K×256]
    unsigned short* pbuf3  = bufX;                               // [100K×256] full X

    // ---- CSR build via counting sort (no global atomics) ----
    hist_kernel<<<NBLK, 256, 0, stream>>>(e_dst, hist);
    bucket_tot_kernel<<<NB, 64, 0, stream>>>(hist, tot);
    bucket_scan_kernel<<<1, 256, 0, stream>>>(tot, bucketStart);
    bucket_base_kernel<<<(NB + 255) / 256, 256, 0, stream>>>(hist, bucketStart);
    scatter1_kernel<<<NBLK, 256, 0, stream>>>(e_src, e_dst, hist, sdst, ssrc);
    csr2_kernel<<<NB, 256, 0, stream>>>(sdst, ssrc, bucketStart, offsets, dis, csr_src);

    // pack W2/W3 into MFMA B-frag split-bf16 planes
    pack_w_kernel<128><<<(16 * 4 * 64 + 255) / 256, 256, 0, stream>>>(W2, whi2, wlo2);
    pack_w_kernel<256><<<(16 * 8 * 64 + 255) / 256, 256, 0, stream>>>(W3, whi3, wlo3);

    // Layer 1 (GEMM-first): t1 = bf16((x@W1)*dis)
    gemm1_kernel<<<N_NODES / 16, 128, 0, stream>>>(x, W1, dis, t1);
    agg_bf16_kernel<128, true><<<N_NODES / 4, 256, 0, stream>>>(t1, csr_src, offsets, dis, b1, table2);

    // Layer 2 (propagate-first)
    agg_bf16_kernel<128, false><<<N_NODES / 4, 256, 0, stream>>>(table2, csr_src, offsets, dis, nullptr, pbuf2);
    mfma_gemm_kernel<128, 1><<<N_NODES / 32, 256, 0, stream>>>(pbuf2, whi2, wlo2, b2, dis, table3);

    // Layer 3 (propagate-first): h3 bf16
    agg_bf16_kernel<256, false><<<N_NODES / 4, 256, 0, stream>>>(table3, csr_src, offsets, dis, nullptr, pbuf3);
    mfma_gemm_kernel<256, 2><<<N_NODES / 32, 256, 0, stream>>>(pbuf3, whi3, wlo3, b3, nullptr, h3);

    // pool + head
    pool_bf16_kernel<<<N_GRAPHS / 4, 256, 0, stream>>>(h3, batch, pooled);
    head_gemm_kernel<<<N_GRAPHS / 16, 256, 0, stream>>>(pooled, Wp, bp, out);
}